// Round 2
// baseline (503.467 us; speedup 1.0000x reference)
//
#include <hip/hip_runtime.h>
#include <hip/hip_bf16.h>

#define BI   4
#define LI   256
#define EI   768
#define DI   1536
#define NI   16
#define RI   48
#define KI   4
#define NDIRS 4
#define F2D  3072              // 2*D
#define MROWS 1024             // B*L

typedef float    floatx4 __attribute__((ext_vector_type(4)));
typedef float    floatx8 __attribute__((ext_vector_type(8)));
typedef _Float16 halfx8  __attribute__((ext_vector_type(8)));

__device__ __forceinline__ int perm_idx(int dir, int j) {
    // PERMS from reference: identity, reverse, transpose(16x16), reverse-transpose
    switch (dir) {
        case 0:  return j;
        case 1:  return 255 - j;
        case 2:  return ((j & 15) << 4) | (j >> 4);
        default: return 255 - (((j & 15) << 4) | (j >> 4));
    }
}

// Split 8 fp32 values into hi/lo fp16 halves: v = hi + lo + O(2^-22 |v|).
__device__ __forceinline__ void split8(floatx8 v, halfx8& hi, halfx8& lo) {
    #pragma unroll
    for (int i = 0; i < 8; ++i) {
        _Float16 h = (_Float16)v[i];
        hi[i] = h;
        lo[i] = (_Float16)(v[i] - (float)h);
    }
}

// One K=32 chunk of high-precision fp32 GEMM via 3x fp16 MFMA.
__device__ __forceinline__ floatx4 mfma_fp32split(floatx8 af, floatx8 bf, floatx4 acc) {
    halfx8 ah, al, bh, bl;
    split8(af, ah, al);
    split8(bf, bh, bl);
    acc = __builtin_amdgcn_mfma_f32_16x16x32_f16(ah, bh, acc, 0, 0, 0);
    acc = __builtin_amdgcn_mfma_f32_16x16x32_f16(ah, bl, acc, 0, 0, 0);
    acc = __builtin_amdgcn_mfma_f32_16x16x32_f16(al, bh, acc, 0, 0, 0);
    return acc;
}

// ---------------------------------------------------------------------------
// GEMM kernels: C[M,N] = A[M,K] * B[N,K]^T, both fp32 K-contiguous row-major.
// Per-wave 16x16 C tile via mfma_f32_16x16x32_f16 (layout:
//   A[m=lane&15][k=quad*8+j], B[n=lane&15][k=quad*8+j],
//   D: col=lane&15, row=quad*4+reg).
// Block = 4 waves stacked along M (64xM, 16xN per block).
// ---------------------------------------------------------------------------

// in_proj: A=hidden_states (1024x768), B=in_proj_w (3072x768), C=xz fp32 (1024x3072)
__global__ __launch_bounds__(256) void k_inproj(const float* __restrict__ A,
                                                const float* __restrict__ Bw,
                                                float* __restrict__ C) {
    int lane = threadIdx.x & 63, wave = threadIdx.x >> 6;
    int m0 = blockIdx.x * 64 + wave * 16;
    int n0 = blockIdx.y * 16;
    int mm = lane & 15, q = lane >> 4;
    const float* pa = A  + (size_t)(m0 + mm) * EI + q * 8;
    const float* pb = Bw + (size_t)(n0 + mm) * EI + q * 8;
    floatx4 acc = {0.f, 0.f, 0.f, 0.f};
    for (int k = 0; k < EI; k += 32)
        acc = mfma_fp32split(*(const floatx8*)(pa + k), *(const floatx8*)(pb + k), acc);
    int col = n0 + mm, rbase = m0 + q * 4;
    for (int r = 0; r < 4; ++r)
        C[(size_t)(rbase + r) * F2D + col] = acc[r];
}

// out_proj: A=ysum (1024x1536), B=out_proj_w (768x1536), C=d_out fp32 (1024x768)
__global__ __launch_bounds__(256) void k_outproj(const float* __restrict__ A,
                                                 const float* __restrict__ Bw,
                                                 float* __restrict__ C) {
    int lane = threadIdx.x & 63, wave = threadIdx.x >> 6;
    int m0 = blockIdx.x * 64 + wave * 16;
    int n0 = blockIdx.y * 16;
    int mm = lane & 15, q = lane >> 4;
    const float* pa = A  + (size_t)(m0 + mm) * DI + q * 8;
    const float* pb = Bw + (size_t)(n0 + mm) * DI + q * 8;
    floatx4 acc = {0.f, 0.f, 0.f, 0.f};
    for (int k = 0; k < DI; k += 32)
        acc = mfma_fp32split(*(const floatx8*)(pa + k), *(const floatx8*)(pb + k), acc);
    int col = n0 + mm, rbase = m0 + q * 4;
    for (int r = 0; r < 4; ++r)
        C[(size_t)(rbase + r) * EI + col] = acc[r];
}

// x_dbl per dir: A=x_bld (1024x1536), B=xproj_w[dir] (80x1536), output split:
//   cols 0..47 -> dtq fp32 (stride 48), 48..63 -> Bm fp32 (stride 16), 64..79 -> Cm fp32
__global__ __launch_bounds__(256) void k_xdbl(const float* __restrict__ xbld,
                                              const float* __restrict__ xw,
                                              float* __restrict__ dtq,
                                              float* __restrict__ Bm,
                                              float* __restrict__ Cm) {
    int dir = blockIdx.z;
    const float* A  = xbld + (size_t)dir * MROWS * DI;
    const float* Bw = xw   + (size_t)dir * 80 * DI;
    int lane = threadIdx.x & 63, wave = threadIdx.x >> 6;
    int m0 = blockIdx.x * 64 + wave * 16;
    int n0 = blockIdx.y * 16;
    int mm = lane & 15, q = lane >> 4;
    const float* pa = A  + (size_t)(m0 + mm) * DI + q * 8;
    const float* pb = Bw + (size_t)(n0 + mm) * DI + q * 8;
    floatx4 acc = {0.f, 0.f, 0.f, 0.f};
    for (int k = 0; k < DI; k += 32)
        acc = mfma_fp32split(*(const floatx8*)(pa + k), *(const floatx8*)(pb + k), acc);
    int col = n0 + mm, rbase = m0 + q * 4;
    for (int r = 0; r < 4; ++r) {
        int row = rbase + r;
        float v = acc[r];
        if (col < 48)
            dtq[((size_t)dir * MROWS + row) * 48 + col] = v;
        else if (col < 64)
            Bm[((size_t)dir * MROWS + row) * 16 + (col - 48)] = v;
        else
            Cm[((size_t)dir * MROWS + row) * 16 + (col - 64)] = v;
    }
}

// delta per dir: A=dtq (1024x48), B=dtproj_w[dir] (1536x48), K=48 (masked tail),
// epilogue: softplus(acc + dtb) -> delta fp32 (1024x1536)
__global__ __launch_bounds__(256) void k_delta(const float* __restrict__ dtq,
                                               const float* __restrict__ dtw,
                                               const float* __restrict__ dtb,
                                               float* __restrict__ delta) {
    int dir = blockIdx.z;
    const float* A  = dtq + (size_t)dir * MROWS * 48;
    const float* Bw = dtw + (size_t)dir * DI * 48;
    int lane = threadIdx.x & 63, wave = threadIdx.x >> 6;
    int m0 = blockIdx.x * 64 + wave * 16;
    int n0 = blockIdx.y * 16;
    int mm = lane & 15, q = lane >> 4;
    const float* pa = A  + (size_t)(m0 + mm) * 48 + q * 8;
    const float* pb = Bw + (size_t)(n0 + mm) * 48 + q * 8;
    floatx4 acc = {0.f, 0.f, 0.f, 0.f};
    // k = 0..31 (all quads valid)
    acc = mfma_fp32split(*(const floatx8*)pa, *(const floatx8*)pb, acc);
    // k = 32..63: only quads 0,1 (k=32..47) valid; zero the rest
    {
        floatx8 af = {}, bf = {};
        if (q < 2) {
            af = *(const floatx8*)(pa + 32);
            bf = *(const floatx8*)(pb + 32);
        }
        acc = mfma_fp32split(af, bf, acc);
    }
    int col = n0 + mm, rbase = m0 + q * 4;
    float bias = dtb[(size_t)dir * DI + col];
    for (int r = 0; r < 4; ++r) {
        int row = rbase + r;
        float v = acc[r] + bias;
        float sp = (v > 20.f) ? v : log1pf(__expf(v));
        delta[((size_t)dir * MROWS + row) * DI + col] = sp;
    }
}

// ---------------------------------------------------------------------------
// Depthwise causal conv (K=4) + bias + silu, on permuted xz x-part.
// Writes x in [dir][row=(b,l_scan)][d] layout, fp32.
// ---------------------------------------------------------------------------
__global__ __launch_bounds__(256) void k_conv(const float* __restrict__ xz,
                                              const float* __restrict__ cw,
                                              const float* __restrict__ cb,
                                              float* __restrict__ xbld) {
    int dir = blockIdx.z;
    int bl = blockIdx.x;            // b*256 + l (scan domain)
    int b = bl >> 8, l = bl & 255;
    int d = blockIdx.y * 256 + threadIdx.x;
    const float* w = cw + ((size_t)dir * DI + d) * KI;
    float s = cb[(size_t)dir * DI + d];
    #pragma unroll
    for (int k = 0; k < KI; ++k) {
        int m = l - 3 + k;
        if (m >= 0) {
            int src = perm_idx(dir, m);
            s += w[k] * xz[((size_t)b * 256 + src) * F2D + d];
        }
    }
    float x = s / (1.f + __expf(-s));       // silu
    xbld[((size_t)dir * MROWS + bl) * DI + d] = x;
}

// ---------------------------------------------------------------------------
// Selective scan. Block = 256 thr = 16(n) x 16(d-slot); one (dir, b, 16 d's)
// per block. LDS-staged operands in 16-step chunks; 16-lane shuffle reduce
// for sum over n; y written to out-domain position perm(j).
// ---------------------------------------------------------------------------
__global__ __launch_bounds__(256) void k_scan(const float* __restrict__ delta,
                                              const float* __restrict__ xbld,
                                              const float* __restrict__ xz,
                                              const float* __restrict__ Bm,
                                              const float* __restrict__ Cm,
                                              const float* __restrict__ A_log,
                                              const float* __restrict__ Dp,
                                              float* __restrict__ ydir) {
    int dblock = blockIdx.x;   // 0..95
    int b      = blockIdx.y;   // 0..3
    int dir    = blockIdx.z;   // 0..3
    int tid = threadIdx.x;
    int n = tid & 15, ds = tid >> 4;
    int d = dblock * 16 + ds;

    __shared__ float sdel[16][16], sx[16][16], sz[16][16],
                     sB[16][16], sC[16][16], sY[16][16];

    float Aval = -__expf(A_log[((size_t)dir * DI + d) * NI + n]);
    float Dpar = Dp[(size_t)dir * DI + d];
    float h = 0.f;

    int jr = tid >> 4, c = tid & 15;   // load/write-phase roles
    const size_t dirrow = (size_t)dir * MROWS;

    for (int j0 = 0; j0 < 256; j0 += 16) {
        // ---- stage 16 steps of operands (coalesced 16-float segments) ----
        {
            int row = b * 256 + j0 + jr;
            sdel[jr][c] = delta[(dirrow + row) * DI + dblock * 16 + c];
            sx[jr][c]   = xbld[(dirrow + row) * DI + dblock * 16 + c];
            int lsrc = perm_idx(dir, j0 + jr);
            sz[jr][c]   = xz[((size_t)b * 256 + lsrc) * F2D + DI + dblock * 16 + c];
            sB[jr][c]   = Bm[(dirrow + row) * 16 + c];
            sC[jr][c]   = Cm[(dirrow + row) * 16 + c];
        }
        __syncthreads();
        // ---- 16 recurrence steps ----
        #pragma unroll
        for (int jj = 0; jj < 16; ++jj) {
            float dv = sdel[jj][ds];
            float xv = sx[jj][ds];
            float a  = __expf(dv * Aval);
            h = fmaf(a, h, dv * xv * sB[jj][n]);
            float p = h * sC[jj][n];
            p += __shfl_xor(p, 1);
            p += __shfl_xor(p, 2);
            p += __shfl_xor(p, 4);
            p += __shfl_xor(p, 8);
            if (n == 0) sY[jj][ds] = p + Dpar * xv;
        }
        __syncthreads();
        // ---- gate by silu(z), write to out-domain ----
        {
            int lout = perm_idx(dir, j0 + jr);
            float zv = sz[jr][c];
            float y  = sY[jr][c];
            float g  = zv / (1.f + __expf(-zv));
            ydir[(dirrow + (size_t)b * 256 + lout) * DI + dblock * 16 + c] = y * g;
        }
        __syncthreads();
    }
}

// sum of 4 direction outputs -> fp32 A-matrix for out_proj
__global__ __launch_bounds__(256) void k_sum(const float* __restrict__ ydir,
                                             float* __restrict__ ysum) {
    int i = blockIdx.x * 256 + threadIdx.x;
    const size_t S = (size_t)MROWS * DI;
    ysum[i] = ydir[i] + ydir[S + i] + ydir[2 * S + i] + ydir[3 * S + i];
}

// ---------------------------------------------------------------------------
extern "C" void kernel_launch(void* const* d_in, const int* in_sizes, int n_in,
                              void* d_out, int out_size, void* d_ws, size_t ws_size,
                              hipStream_t stream) {
    const float* hs   = (const float*)d_in[0];   // (B,L,E)
    const float* wip  = (const float*)d_in[1];   // (2D,E)
    const float* wop  = (const float*)d_in[2];   // (E,D)
    const float* cw   = (const float*)d_in[3];   // (NDIR,D,K)
    const float* cb   = (const float*)d_in[4];   // (NDIR,D)
    const float* xw   = (const float*)d_in[5];   // (NDIR,80,D)
    const float* dtw  = (const float*)d_in[6];   // (NDIR,D,R)
    const float* dtb  = (const float*)d_in[7];   // (NDIR,D)
    const float* alog = (const float*)d_in[8];   // (NDIR,D,N)
    const float* dpar = (const float*)d_in[9];   // (NDIR,D)
    float* out = (float*)d_out;                  // (B,L,E)

    char* p = (char*)d_ws;
    float* xz    = (float*)p; p += (size_t)MROWS * F2D * 4;         // 12.6 MB
    float* xbld  = (float*)p; p += (size_t)NDIRS * MROWS * DI * 4;  // 25.2 MB
    float* dtq   = (float*)p; p += (size_t)NDIRS * MROWS * 48 * 4;  // 0.79 MB
    float* Bmb   = (float*)p; p += (size_t)NDIRS * MROWS * 16 * 4;  // 0.26 MB
    float* Cmb   = (float*)p; p += (size_t)NDIRS * MROWS * 16 * 4;  // 0.26 MB
    float* delta = (float*)p; p += (size_t)NDIRS * MROWS * DI * 4;  // 25.2 MB
    float* ydir  = (float*)p; p += (size_t)NDIRS * MROWS * DI * 4;  // 25.2 MB
    float* ysum  = (float*)p; p += (size_t)MROWS * DI * 4;          //  6.3 MB

    k_inproj <<<dim3(MROWS / 64, F2D / 16), 256, 0, stream>>>(hs, wip, xz);
    k_conv   <<<dim3(MROWS, DI / 256, NDIRS), 256, 0, stream>>>(xz, cw, cb, xbld);
    k_xdbl   <<<dim3(MROWS / 64, 80 / 16, NDIRS), 256, 0, stream>>>(xbld, xw, dtq, Bmb, Cmb);
    k_delta  <<<dim3(MROWS / 64, DI / 16, NDIRS), 256, 0, stream>>>(dtq, dtw, dtb, delta);
    k_scan   <<<dim3(DI / 16, BI, NDIRS), 256, 0, stream>>>(delta, xbld, xz, Bmb, Cmb, alog, dpar, ydir);
    k_sum    <<<dim3((MROWS * DI) / 256), 256, 0, stream>>>(ydir, ysum);
    k_outproj<<<dim3(MROWS / 64, EI / 16), 256, 0, stream>>>(ysum, wop, out);
}

// Round 3
// 351.245 us; speedup vs baseline: 1.4334x; 1.4334x over previous
//
#include <hip/hip_runtime.h>
#include <hip/hip_bf16.h>

#define BI   4
#define LI   256
#define EI   768
#define DI   1536
#define NI   16
#define RI   48
#define KI   4
#define NDIRS 4
#define F2D  3072              // 2*D
#define MROWS 1024             // B*L

typedef float    floatx4 __attribute__((ext_vector_type(4)));
typedef _Float16 halfx8  __attribute__((ext_vector_type(8)));

typedef __attribute__((address_space(3))) unsigned lds_u32;
typedef __attribute__((address_space(1))) const unsigned glb_u32;

__device__ __forceinline__ void load16(const _Float16* g, _Float16* l) {
    __builtin_amdgcn_global_load_lds((glb_u32*)g, (lds_u32*)l, 16, 0, 0);
}

__device__ __forceinline__ int perm_idx(int dir, int j) {
    switch (dir) {
        case 0:  return j;
        case 1:  return 255 - j;
        case 2:  return ((j & 15) << 4) | (j >> 4);
        default: return 255 - (((j & 15) << 4) | (j >> 4));
    }
}

// ---------------------------------------------------------------------------
// Tiled hi/lo-fp16 GEMM core. C[M,N] = A[M,K]*B[N,K]^T with A,B pre-split to
// hi/lo fp16 (a = ah + al, |al| <= 2^-11|a|). 4 waves/block, wave grid
// (4/WGN) x WGN, fragment grid FM x FN of 16x16 tiles. LDS tiles [rows][32]
// fp16, unpadded (global_load_lds lane-order requirement). K consumed in
// chunks of 32. acc += ah*bh + ah*bl + al*bh  (al*bl term ~2^-22, dropped).
// ---------------------------------------------------------------------------
template<int BM, int BN, int WGN, int FM, int FN>
__device__ __forceinline__ void gemm_core(const _Float16* __restrict__ Ah,
                                          const _Float16* __restrict__ Al, int lda,
                                          const _Float16* __restrict__ Bh,
                                          const _Float16* __restrict__ Bl, int ldb,
                                          int nChunks, _Float16* smem,
                                          floatx4 (&acc)[FM][FN]) {
    const int tid = threadIdx.x, lane = tid & 63, wave = tid >> 6;
    const int wave_m = wave / WGN, wave_n = wave % WGN;
    _Float16* sAh = smem;
    _Float16* sAl = smem + BM * 32;
    _Float16* sBh = smem + BM * 64;
    _Float16* sBl = smem + BM * 64 + BN * 32;
    const int rr = lane & 15, koff = (lane >> 4) * 8;
    const int arow = wave_m * FM * 16, brow = wave_n * FN * 16;

    for (int c = 0; c < nChunks; ++c) {
        // stage A/B (hi & lo) tiles: 16B per lane-load, row-major [r][32]
        for (int idx = tid; idx < BM * 4; idx += 256) {
            int r = idx >> 2, s = (idx & 3) * 8;
            load16(Ah + (size_t)r * lda + c * 32 + s, sAh + idx * 8);
            load16(Al + (size_t)r * lda + c * 32 + s, sAl + idx * 8);
        }
        for (int idx = tid; idx < BN * 4; idx += 256) {
            int r = idx >> 2, s = (idx & 3) * 8;
            load16(Bh + (size_t)r * ldb + c * 32 + s, sBh + idx * 8);
            load16(Bl + (size_t)r * ldb + c * 32 + s, sBl + idx * 8);
        }
        asm volatile("s_waitcnt vmcnt(0)" ::: "memory");
        __syncthreads();

        halfx8 ahf[FM], alf[FM], bhf[FN], blf[FN];
        #pragma unroll
        for (int i = 0; i < FM; ++i) {
            ahf[i] = *(const halfx8*)(sAh + (arow + i * 16 + rr) * 32 + koff);
            alf[i] = *(const halfx8*)(sAl + (arow + i * 16 + rr) * 32 + koff);
        }
        #pragma unroll
        for (int j = 0; j < FN; ++j) {
            bhf[j] = *(const halfx8*)(sBh + (brow + j * 16 + rr) * 32 + koff);
            blf[j] = *(const halfx8*)(sBl + (brow + j * 16 + rr) * 32 + koff);
        }
        #pragma unroll
        for (int i = 0; i < FM; ++i)
            #pragma unroll
            for (int j = 0; j < FN; ++j) {
                acc[i][j] = __builtin_amdgcn_mfma_f32_16x16x32_f16(ahf[i], bhf[j], acc[i][j], 0, 0, 0);
                acc[i][j] = __builtin_amdgcn_mfma_f32_16x16x32_f16(ahf[i], blf[j], acc[i][j], 0, 0, 0);
                acc[i][j] = __builtin_amdgcn_mfma_f32_16x16x32_f16(alf[i], bhf[j], acc[i][j], 0, 0, 0);
            }
        __syncthreads();
    }
}

// ---------------------------------------------------------------------------
// zero-init helper (ws/out are poisoned 0xAA before every launch)
__global__ __launch_bounds__(256) void k_zero(float* __restrict__ a, int n) {
    int i = blockIdx.x * 256 + threadIdx.x;
    if (i < n) a[i] = 0.f;
}

// split all static operands to hi/lo fp16 (dtw also padded K 48->64)
__global__ __launch_bounds__(256) void k_splitall(
        const float* __restrict__ hs,  const float* __restrict__ wip,
        const float* __restrict__ wop, const float* __restrict__ xw,
        const float* __restrict__ dtw,
        _Float16* __restrict__ hsh,  _Float16* __restrict__ hsl,
        _Float16* __restrict__ wiph, _Float16* __restrict__ wipl,
        _Float16* __restrict__ woph, _Float16* __restrict__ wopl,
        _Float16* __restrict__ xwh,  _Float16* __restrict__ xwl,
        _Float16* __restrict__ dtwh, _Float16* __restrict__ dtwl) {
    int idx = blockIdx.x * 256 + threadIdx.x;
    float v; _Float16 *dh, *dl; int off;
    if (idx < 786432)        { off = idx;           v = hs[off];  dh = hsh;  dl = hsl;  }
    else if (idx < 3145728)  { off = idx - 786432;  v = wip[off]; dh = wiph; dl = wipl; }
    else if (idx < 4325376)  { off = idx - 3145728; v = wop[off]; dh = woph; dl = wopl; }
    else if (idx < 4816896)  { off = idx - 4325376; v = xw[off];  dh = xwh;  dl = xwl;  }
    else {
        int t = idx - 4816896;          // [dir*1536 + d][64] padded
        int col = t & 63, dr = t >> 6;
        v = (col < 48) ? dtw[(size_t)dr * 48 + col] : 0.f;
        _Float16 h = (_Float16)v;
        dtwh[t] = h; dtwl[t] = (_Float16)(v - (float)h);
        return;
    }
    _Float16 h = (_Float16)v;
    dh[off] = h; dl[off] = (_Float16)(v - (float)h);
}

// ---------------------------------------------------------------------------
// in_proj: (1024x768)*(3072x768)^T -> xz fp32 (1024x3072)
__global__ __launch_bounds__(256) void k_inproj_t(const _Float16* __restrict__ Ah,
                                                  const _Float16* __restrict__ Al,
                                                  const _Float16* __restrict__ Bh,
                                                  const _Float16* __restrict__ Bl,
                                                  float* __restrict__ C) {
    __shared__ _Float16 smem[192 * 64];
    int row0 = blockIdx.x * 64, col0 = blockIdx.y * 128;
    floatx4 acc[2][4] = {};
    gemm_core<64, 128, 2, 2, 4>(Ah + (size_t)row0 * EI, Al + (size_t)row0 * EI, EI,
                                Bh + (size_t)col0 * EI, Bl + (size_t)col0 * EI, EI,
                                EI / 32, smem, acc);
    int lane = threadIdx.x & 63, wave = threadIdx.x >> 6;
    int cc = lane & 15, q = lane >> 4;
    int rbase = row0 + (wave >> 1) * 32, cbase = col0 + (wave & 1) * 64;
    #pragma unroll
    for (int i = 0; i < 2; ++i)
        #pragma unroll
        for (int j = 0; j < 4; ++j)
            #pragma unroll
            for (int r = 0; r < 4; ++r)
                C[(size_t)(rbase + i * 16 + q * 4 + r) * F2D + cbase + j * 16 + cc] = acc[i][j][r];
}

// out_proj: (1024x1536)*(768x1536)^T -> out fp32 (1024x768), K-split x4 + atomic
__global__ __launch_bounds__(256) void k_outproj_t(const _Float16* __restrict__ Ah,
                                                   const _Float16* __restrict__ Al,
                                                   const _Float16* __restrict__ Bh,
                                                   const _Float16* __restrict__ Bl,
                                                   float* __restrict__ C) {
    __shared__ _Float16 smem[192 * 64];
    int row0 = blockIdx.x * 64, col0 = blockIdx.y * 128, k0 = blockIdx.z * 384;
    floatx4 acc[2][4] = {};
    gemm_core<64, 128, 2, 2, 4>(Ah + (size_t)row0 * DI + k0, Al + (size_t)row0 * DI + k0, DI,
                                Bh + (size_t)col0 * DI + k0, Bl + (size_t)col0 * DI + k0, DI,
                                12, smem, acc);
    int lane = threadIdx.x & 63, wave = threadIdx.x >> 6;
    int cc = lane & 15, q = lane >> 4;
    int rbase = row0 + (wave >> 1) * 32, cbase = col0 + (wave & 1) * 64;
    #pragma unroll
    for (int i = 0; i < 2; ++i)
        #pragma unroll
        for (int j = 0; j < 4; ++j)
            #pragma unroll
            for (int r = 0; r < 4; ++r)
                atomicAdd(&C[(size_t)(rbase + i * 16 + q * 4 + r) * EI + cbase + j * 16 + cc], acc[i][j][r]);
}

// x_dbl: per dir (1024x1536)*(80x1536)^T -> xdbl_acc fp32, K-split x8 + atomic
__global__ __launch_bounds__(256) void k_xdbl_t(const _Float16* __restrict__ xh,
                                                const _Float16* __restrict__ xl,
                                                const _Float16* __restrict__ xwh,
                                                const _Float16* __restrict__ xwl,
                                                float* __restrict__ C) {
    __shared__ _Float16 smem[208 * 64];
    int row0 = blockIdx.x * 128, dir = blockIdx.y, k0 = blockIdx.z * 192;
    floatx4 acc[2][5] = {};
    const size_t abase = ((size_t)dir * MROWS + row0) * DI + k0;
    const size_t bbase = (size_t)dir * 80 * DI + k0;
    gemm_core<128, 80, 1, 2, 5>(xh + abase, xl + abase, DI,
                                xwh + bbase, xwl + bbase, DI, 6, smem, acc);
    int lane = threadIdx.x & 63, wave = threadIdx.x >> 6;
    int cc = lane & 15, q = lane >> 4;
    int rbase = row0 + wave * 32;
    #pragma unroll
    for (int i = 0; i < 2; ++i)
        #pragma unroll
        for (int j = 0; j < 5; ++j)
            #pragma unroll
            for (int r = 0; r < 4; ++r)
                atomicAdd(&C[((size_t)dir * MROWS + rbase + i * 16 + q * 4 + r) * 80 + j * 16 + cc],
                          acc[i][j][r]);
}

// xdbl epilogue: split cols -> dtq hi/lo (padded to 64), Bm, Cm fp32
__global__ __launch_bounds__(256) void k_xsplit(const float* __restrict__ acc,
                                                _Float16* __restrict__ dtqh,
                                                _Float16* __restrict__ dtql,
                                                float* __restrict__ Bm,
                                                float* __restrict__ Cm) {
    int idx = blockIdx.x * 256 + threadIdx.x;   // < 4*1024*112
    int dir = idx / (MROWS * 112);
    int rem = idx - dir * MROWS * 112;
    int row = rem / 112, col = rem - row * 112;
    size_t rbase = (size_t)dir * MROWS + row;
    if (col < 64) {
        float v = (col < 48) ? acc[rbase * 80 + col] : 0.f;
        _Float16 h = (_Float16)v;
        dtqh[rbase * 64 + col] = h;
        dtql[rbase * 64 + col] = (_Float16)(v - (float)h);
    } else if (col < 80) {
        Bm[rbase * 16 + (col - 64)] = acc[rbase * 80 + (col - 16)];
    } else {
        Cm[rbase * 16 + (col - 80)] = acc[rbase * 80 + (col - 16)];
    }
}

// delta: per dir (1024x64pad)*(1536x64pad)^T, epilogue softplus(.+dtb) -> fp32
__global__ __launch_bounds__(256) void k_delta_t(const _Float16* __restrict__ dtqh,
                                                 const _Float16* __restrict__ dtql,
                                                 const _Float16* __restrict__ dtwh,
                                                 const _Float16* __restrict__ dtwl,
                                                 const float* __restrict__ dtb,
                                                 float* __restrict__ delta) {
    __shared__ _Float16 smem[192 * 64];
    int row0 = blockIdx.x * 64, col0 = blockIdx.y * 128, dir = blockIdx.z;
    floatx4 acc[2][4] = {};
    const size_t abase = ((size_t)dir * MROWS + row0) * 64;
    const size_t bbase = ((size_t)dir * DI + col0) * 64;
    gemm_core<64, 128, 2, 2, 4>(dtqh + abase, dtql + abase, 64,
                                dtwh + bbase, dtwl + bbase, 64, 2, smem, acc);
    int lane = threadIdx.x & 63, wave = threadIdx.x >> 6;
    int cc = lane & 15, q = lane >> 4;
    int rbase = row0 + (wave >> 1) * 32, cbase = col0 + (wave & 1) * 64;
    #pragma unroll
    for (int i = 0; i < 2; ++i)
        #pragma unroll
        for (int j = 0; j < 4; ++j) {
            int col = cbase + j * 16 + cc;
            float bias = dtb[(size_t)dir * DI + col];
            #pragma unroll
            for (int r = 0; r < 4; ++r) {
                float v = acc[i][j][r] + bias;
                float sp = (v > 20.f) ? v : log1pf(__expf(v));
                delta[((size_t)dir * MROWS + rbase + i * 16 + q * 4 + r) * DI + col] = sp;
            }
        }
}

// ---------------------------------------------------------------------------
// Depthwise causal conv (K=4) + bias + silu on permuted xz x-part,
// output split to hi/lo fp16 [dir][b*256+l_scan][D].
__global__ __launch_bounds__(256) void k_conv(const float* __restrict__ xz,
                                              const float* __restrict__ cw,
                                              const float* __restrict__ cb,
                                              _Float16* __restrict__ xh,
                                              _Float16* __restrict__ xl) {
    int dir = blockIdx.z;
    int bl = blockIdx.x;
    int b = bl >> 8, l = bl & 255;
    int d = blockIdx.y * 256 + threadIdx.x;
    const float* w = cw + ((size_t)dir * DI + d) * KI;
    float s = cb[(size_t)dir * DI + d];
    #pragma unroll
    for (int k = 0; k < KI; ++k) {
        int m = l - 3 + k;
        if (m >= 0) {
            int src = perm_idx(dir, m);
            s += w[k] * xz[((size_t)b * 256 + src) * F2D + d];
        }
    }
    float x = s / (1.f + __expf(-s));
    _Float16 h = (_Float16)x;
    size_t o = ((size_t)dir * MROWS + bl) * DI + d;
    xh[o] = h;
    xl[o] = (_Float16)(x - (float)h);
}

// ---------------------------------------------------------------------------
// Selective scan (unchanged structure; x read as hi+lo).
__global__ __launch_bounds__(256) void k_scan(const float* __restrict__ delta,
                                              const _Float16* __restrict__ xhg,
                                              const _Float16* __restrict__ xlg,
                                              const float* __restrict__ xz,
                                              const float* __restrict__ Bm,
                                              const float* __restrict__ Cm,
                                              const float* __restrict__ A_log,
                                              const float* __restrict__ Dp,
                                              float* __restrict__ ydir) {
    int dblock = blockIdx.x, b = blockIdx.y, dir = blockIdx.z;
    int tid = threadIdx.x;
    int n = tid & 15, ds = tid >> 4;
    int d = dblock * 16 + ds;

    __shared__ float sdel[16][16], sx[16][16], sz[16][16],
                     sB[16][16], sC[16][16], sY[16][16];

    float Aval = -__expf(A_log[((size_t)dir * DI + d) * NI + n]);
    float Dpar = Dp[(size_t)dir * DI + d];
    float h = 0.f;

    int jr = tid >> 4, c = tid & 15;
    const size_t dirrow = (size_t)dir * MROWS;

    for (int j0 = 0; j0 < 256; j0 += 16) {
        {
            int row = b * 256 + j0 + jr;
            size_t o = (dirrow + row) * DI + dblock * 16 + c;
            sdel[jr][c] = delta[o];
            sx[jr][c]   = (float)xhg[o] + (float)xlg[o];
            int lsrc = perm_idx(dir, j0 + jr);
            sz[jr][c]   = xz[((size_t)b * 256 + lsrc) * F2D + DI + dblock * 16 + c];
            sB[jr][c]   = Bm[(dirrow + row) * 16 + c];
            sC[jr][c]   = Cm[(dirrow + row) * 16 + c];
        }
        __syncthreads();
        #pragma unroll
        for (int jj = 0; jj < 16; ++jj) {
            float dv = sdel[jj][ds];
            float xv = sx[jj][ds];
            float a  = __expf(dv * Aval);
            h = fmaf(a, h, dv * xv * sB[jj][n]);
            float p = h * sC[jj][n];
            p += __shfl_xor(p, 1);
            p += __shfl_xor(p, 2);
            p += __shfl_xor(p, 4);
            p += __shfl_xor(p, 8);
            if (n == 0) sY[jj][ds] = p + Dpar * xv;
        }
        __syncthreads();
        {
            int lout = perm_idx(dir, j0 + jr);
            float zv = sz[jr][c];
            float y  = sY[jr][c];
            float g  = zv / (1.f + __expf(-zv));
            ydir[(dirrow + (size_t)b * 256 + lout) * DI + dblock * 16 + c] = y * g;
        }
        __syncthreads();
    }
}

// sum of 4 direction outputs -> hi/lo fp16 for out_proj A-operand
__global__ __launch_bounds__(256) void k_sum(const float* __restrict__ ydir,
                                             _Float16* __restrict__ yh,
                                             _Float16* __restrict__ yl) {
    int i = blockIdx.x * 256 + threadIdx.x;
    const size_t S = (size_t)MROWS * DI;
    float s = ydir[i] + ydir[S + i] + ydir[2 * S + i] + ydir[3 * S + i];
    _Float16 h = (_Float16)s;
    yh[i] = h;
    yl[i] = (_Float16)(s - (float)h);
}

// ---------------------------------------------------------------------------
extern "C" void kernel_launch(void* const* d_in, const int* in_sizes, int n_in,
                              void* d_out, int out_size, void* d_ws, size_t ws_size,
                              hipStream_t stream) {
    const float* hs   = (const float*)d_in[0];
    const float* wip  = (const float*)d_in[1];
    const float* wop  = (const float*)d_in[2];
    const float* cw   = (const float*)d_in[3];
    const float* cb   = (const float*)d_in[4];
    const float* xw   = (const float*)d_in[5];
    const float* dtw  = (const float*)d_in[6];
    const float* dtb  = (const float*)d_in[7];
    const float* alog = (const float*)d_in[8];
    const float* dpar = (const float*)d_in[9];
    float* out = (float*)d_out;

    char* p = (char*)d_ws;
    auto alloc_f32 = [&](size_t n) { float* r = (float*)p; p += n * 4; return r; };
    auto alloc_f16 = [&](size_t n) { _Float16* r = (_Float16*)p; p += n * 2; return r; };

    _Float16* hsh  = alloc_f16(786432);
    _Float16* hsl  = alloc_f16(786432);
    _Float16* wiph = alloc_f16(2359296);
    _Float16* wipl = alloc_f16(2359296);
    _Float16* woph = alloc_f16(1179648);
    _Float16* wopl = alloc_f16(1179648);
    _Float16* xwh  = alloc_f16(491520);
    _Float16* xwl  = alloc_f16(491520);
    _Float16* dtwh = alloc_f16((size_t)NDIRS * DI * 64);
    _Float16* dtwl = alloc_f16((size_t)NDIRS * DI * 64);
    float*    xz   = alloc_f32((size_t)MROWS * F2D);
    _Float16* xh   = alloc_f16((size_t)NDIRS * MROWS * DI);
    _Float16* xl   = alloc_f16((size_t)NDIRS * MROWS * DI);
    float*    xdba = alloc_f32((size_t)NDIRS * MROWS * 80);
    _Float16* dtqh = alloc_f16((size_t)NDIRS * MROWS * 64);
    _Float16* dtql = alloc_f16((size_t)NDIRS * MROWS * 64);
    float*    Bmb  = alloc_f32((size_t)NDIRS * MROWS * 16);
    float*    Cmb  = alloc_f32((size_t)NDIRS * MROWS * 16);
    float*    delta= alloc_f32((size_t)NDIRS * MROWS * DI);
    float*    ydir = alloc_f32((size_t)NDIRS * MROWS * DI);
    _Float16* yh   = alloc_f16((size_t)MROWS * DI);
    _Float16* yl   = alloc_f16((size_t)MROWS * DI);

    k_zero    <<<dim3(1280), 256, 0, stream>>>(xdba, NDIRS * MROWS * 80);
    k_zero    <<<dim3(3072), 256, 0, stream>>>(out, MROWS * EI);
    k_splitall<<<dim3(20352), 256, 0, stream>>>(hs, wip, wop, xw, dtw,
                                                hsh, hsl, wiph, wipl, woph, wopl,
                                                xwh, xwl, dtwh, dtwl);
    k_inproj_t<<<dim3(16, 24), 256, 0, stream>>>(hsh, hsl, wiph, wipl, xz);
    k_conv    <<<dim3(MROWS, DI / 256, NDIRS), 256, 0, stream>>>(xz, cw, cb, xh, xl);
    k_xdbl_t  <<<dim3(8, NDIRS, 8), 256, 0, stream>>>(xh, xl, xwh, xwl, xdba);
    k_xsplit  <<<dim3(1792), 256, 0, stream>>>(xdba, dtqh, dtql, Bmb, Cmb);
    k_delta_t <<<dim3(16, 12, NDIRS), 256, 0, stream>>>(dtqh, dtql, dtwh, dtwl, dtb, delta);
    k_scan    <<<dim3(DI / 16, BI, NDIRS), 256, 0, stream>>>(delta, xh, xl, xz, Bmb, Cmb,
                                                             alog, dpar, ydir);
    k_sum     <<<dim3((MROWS * DI) / 256), 256, 0, stream>>>(ydir, yh, yl);
    k_outproj_t<<<dim3(16, 6, 4), 256, 0, stream>>>(yh, yl, woph, wopl, out);
}

// Round 4
// 334.836 us; speedup vs baseline: 1.5036x; 1.0490x over previous
//
#include <hip/hip_runtime.h>
#include <hip/hip_bf16.h>

#define BI   4
#define LI   256
#define EI   768
#define DI   1536
#define NI   16
#define RI   48
#define KI   4
#define NDIRS 4
#define F2D  3072              // 2*D
#define MROWS 1024             // B*L

typedef float    floatx2 __attribute__((ext_vector_type(2)));
typedef float    floatx4 __attribute__((ext_vector_type(4)));
typedef _Float16 halfx2  __attribute__((ext_vector_type(2)));
typedef _Float16 halfx8  __attribute__((ext_vector_type(8)));

typedef __attribute__((address_space(3))) unsigned lds_u32;
typedef __attribute__((address_space(1))) const unsigned glb_u32;

__device__ __forceinline__ void load16(const _Float16* g, _Float16* l) {
    __builtin_amdgcn_global_load_lds((glb_u32*)g, (lds_u32*)l, 16, 0, 0);
}

__device__ __forceinline__ int perm_idx(int dir, int j) {
    switch (dir) {
        case 0:  return j;
        case 1:  return 255 - j;
        case 2:  return ((j & 15) << 4) | (j >> 4);
        default: return 255 - (((j & 15) << 4) | (j >> 4));
    }
}

// ---------------------------------------------------------------------------
// Tiled hi/lo-fp16 GEMM core. C[M,N] = A[M,K]*B[N,K]^T with A,B pre-split to
// hi/lo fp16 (a = ah + al, |al| <= 2^-11|a|). 4 waves/block, wave grid
// (4/WGN) x WGN, fragment grid FM x FN of 16x16 tiles. LDS tiles [rows][32]
// fp16, unpadded (global_load_lds lane-order requirement). K consumed in
// chunks of 32. acc += ah*bh + ah*bl + al*bh  (al*bl term ~2^-22, dropped).
// ---------------------------------------------------------------------------
template<int BM, int BN, int WGN, int FM, int FN>
__device__ __forceinline__ void gemm_core(const _Float16* __restrict__ Ah,
                                          const _Float16* __restrict__ Al, int lda,
                                          const _Float16* __restrict__ Bh,
                                          const _Float16* __restrict__ Bl, int ldb,
                                          int nChunks, _Float16* smem,
                                          floatx4 (&acc)[FM][FN]) {
    const int tid = threadIdx.x, lane = tid & 63, wave = tid >> 6;
    const int wave_m = wave / WGN, wave_n = wave % WGN;
    _Float16* sAh = smem;
    _Float16* sAl = smem + BM * 32;
    _Float16* sBh = smem + BM * 64;
    _Float16* sBl = smem + BM * 64 + BN * 32;
    const int rr = lane & 15, koff = (lane >> 4) * 8;
    const int arow = wave_m * FM * 16, brow = wave_n * FN * 16;

    for (int c = 0; c < nChunks; ++c) {
        for (int idx = tid; idx < BM * 4; idx += 256) {
            int r = idx >> 2, s = (idx & 3) * 8;
            load16(Ah + (size_t)r * lda + c * 32 + s, sAh + idx * 8);
            load16(Al + (size_t)r * lda + c * 32 + s, sAl + idx * 8);
        }
        for (int idx = tid; idx < BN * 4; idx += 256) {
            int r = idx >> 2, s = (idx & 3) * 8;
            load16(Bh + (size_t)r * ldb + c * 32 + s, sBh + idx * 8);
            load16(Bl + (size_t)r * ldb + c * 32 + s, sBl + idx * 8);
        }
        asm volatile("s_waitcnt vmcnt(0)" ::: "memory");
        __syncthreads();

        halfx8 ahf[FM], alf[FM], bhf[FN], blf[FN];
        #pragma unroll
        for (int i = 0; i < FM; ++i) {
            ahf[i] = *(const halfx8*)(sAh + (arow + i * 16 + rr) * 32 + koff);
            alf[i] = *(const halfx8*)(sAl + (arow + i * 16 + rr) * 32 + koff);
        }
        #pragma unroll
        for (int j = 0; j < FN; ++j) {
            bhf[j] = *(const halfx8*)(sBh + (brow + j * 16 + rr) * 32 + koff);
            blf[j] = *(const halfx8*)(sBl + (brow + j * 16 + rr) * 32 + koff);
        }
        #pragma unroll
        for (int i = 0; i < FM; ++i)
            #pragma unroll
            for (int j = 0; j < FN; ++j) {
                acc[i][j] = __builtin_amdgcn_mfma_f32_16x16x32_f16(ahf[i], bhf[j], acc[i][j], 0, 0, 0);
                acc[i][j] = __builtin_amdgcn_mfma_f32_16x16x32_f16(ahf[i], blf[j], acc[i][j], 0, 0, 0);
                acc[i][j] = __builtin_amdgcn_mfma_f32_16x16x32_f16(alf[i], bhf[j], acc[i][j], 0, 0, 0);
            }
        __syncthreads();
    }
}

// ---------------------------------------------------------------------------
__global__ __launch_bounds__(256) void k_zero(float* __restrict__ a, int n) {
    int i = blockIdx.x * 256 + threadIdx.x;
    if (i < n) a[i] = 0.f;
}

// split all static operands to hi/lo fp16 (dtw also padded K 48->64)
__global__ __launch_bounds__(256) void k_splitall(
        const float* __restrict__ hs,  const float* __restrict__ wip,
        const float* __restrict__ wop, const float* __restrict__ xw,
        const float* __restrict__ dtw,
        _Float16* __restrict__ hsh,  _Float16* __restrict__ hsl,
        _Float16* __restrict__ wiph, _Float16* __restrict__ wipl,
        _Float16* __restrict__ woph, _Float16* __restrict__ wopl,
        _Float16* __restrict__ xwh,  _Float16* __restrict__ xwl,
        _Float16* __restrict__ dtwh, _Float16* __restrict__ dtwl) {
    int idx = blockIdx.x * 256 + threadIdx.x;
    float v; _Float16 *dh, *dl; int off;
    if (idx < 786432)        { off = idx;           v = hs[off];  dh = hsh;  dl = hsl;  }
    else if (idx < 3145728)  { off = idx - 786432;  v = wip[off]; dh = wiph; dl = wipl; }
    else if (idx < 4325376)  { off = idx - 3145728; v = wop[off]; dh = woph; dl = wopl; }
    else if (idx < 4816896)  { off = idx - 4325376; v = xw[off];  dh = xwh;  dl = xwl;  }
    else {
        int t = idx - 4816896;          // [dir*1536 + d][64] padded
        int col = t & 63, dr = t >> 6;
        v = (col < 48) ? dtw[(size_t)dr * 48 + col] : 0.f;
        _Float16 h = (_Float16)v;
        dtwh[t] = h; dtwl[t] = (_Float16)(v - (float)h);
        return;
    }
    _Float16 h = (_Float16)v;
    dh[off] = h; dl[off] = (_Float16)(v - (float)h);
}

// ---------------------------------------------------------------------------
// in_proj: (1024x768)*(3072x768)^T -> xz fp32 (1024x3072)
__global__ __launch_bounds__(256) void k_inproj_t(const _Float16* __restrict__ Ah,
                                                  const _Float16* __restrict__ Al,
                                                  const _Float16* __restrict__ Bh,
                                                  const _Float16* __restrict__ Bl,
                                                  float* __restrict__ C) {
    __shared__ _Float16 smem[192 * 64];
    int row0 = blockIdx.x * 64, col0 = blockIdx.y * 128;
    floatx4 acc[2][4] = {};
    gemm_core<64, 128, 2, 2, 4>(Ah + (size_t)row0 * EI, Al + (size_t)row0 * EI, EI,
                                Bh + (size_t)col0 * EI, Bl + (size_t)col0 * EI, EI,
                                EI / 32, smem, acc);
    int lane = threadIdx.x & 63, wave = threadIdx.x >> 6;
    int cc = lane & 15, q = lane >> 4;
    int rbase = row0 + (wave >> 1) * 32, cbase = col0 + (wave & 1) * 64;
    #pragma unroll
    for (int i = 0; i < 2; ++i)
        #pragma unroll
        for (int j = 0; j < 4; ++j)
            #pragma unroll
            for (int r = 0; r < 4; ++r)
                C[(size_t)(rbase + i * 16 + q * 4 + r) * F2D + cbase + j * 16 + cc] = acc[i][j][r];
}

// out_proj: (1024x1536)*(768x1536)^T -> out fp32 (1024x768), K-split x4 + atomic
__global__ __launch_bounds__(256) void k_outproj_t(const _Float16* __restrict__ Ah,
                                                   const _Float16* __restrict__ Al,
                                                   const _Float16* __restrict__ Bh,
                                                   const _Float16* __restrict__ Bl,
                                                   float* __restrict__ C) {
    __shared__ _Float16 smem[192 * 64];
    int row0 = blockIdx.x * 64, col0 = blockIdx.y * 128, k0 = blockIdx.z * 384;
    floatx4 acc[2][4] = {};
    gemm_core<64, 128, 2, 2, 4>(Ah + (size_t)row0 * DI + k0, Al + (size_t)row0 * DI + k0, DI,
                                Bh + (size_t)col0 * DI + k0, Bl + (size_t)col0 * DI + k0, DI,
                                12, smem, acc);
    int lane = threadIdx.x & 63, wave = threadIdx.x >> 6;
    int cc = lane & 15, q = lane >> 4;
    int rbase = row0 + (wave >> 1) * 32, cbase = col0 + (wave & 1) * 64;
    #pragma unroll
    for (int i = 0; i < 2; ++i)
        #pragma unroll
        for (int j = 0; j < 4; ++j)
            #pragma unroll
            for (int r = 0; r < 4; ++r)
                atomicAdd(&C[(size_t)(rbase + i * 16 + q * 4 + r) * EI + cbase + j * 16 + cc], acc[i][j][r]);
}

// x_dbl: per dir (1024x1536)*(80x1536)^T -> xdbl_acc fp32, K-split x8 + atomic
__global__ __launch_bounds__(256) void k_xdbl_t(const _Float16* __restrict__ xh,
                                                const _Float16* __restrict__ xl,
                                                const _Float16* __restrict__ xwh,
                                                const _Float16* __restrict__ xwl,
                                                float* __restrict__ C) {
    __shared__ _Float16 smem[208 * 64];
    int row0 = blockIdx.x * 128, dir = blockIdx.y, k0 = blockIdx.z * 192;
    floatx4 acc[2][5] = {};
    const size_t abase = ((size_t)dir * MROWS + row0) * DI + k0;
    const size_t bbase = (size_t)dir * 80 * DI + k0;
    gemm_core<128, 80, 1, 2, 5>(xh + abase, xl + abase, DI,
                                xwh + bbase, xwl + bbase, DI, 6, smem, acc);
    int lane = threadIdx.x & 63, wave = threadIdx.x >> 6;
    int cc = lane & 15, q = lane >> 4;
    int rbase = row0 + wave * 32;
    #pragma unroll
    for (int i = 0; i < 2; ++i)
        #pragma unroll
        for (int j = 0; j < 5; ++j)
            #pragma unroll
            for (int r = 0; r < 4; ++r)
                atomicAdd(&C[((size_t)dir * MROWS + rbase + i * 16 + q * 4 + r) * 80 + j * 16 + cc],
                          acc[i][j][r]);
}

// xdbl epilogue: split cols -> dtq hi/lo (padded to 64), Bm, Cm fp32
__global__ __launch_bounds__(256) void k_xsplit(const float* __restrict__ acc,
                                                _Float16* __restrict__ dtqh,
                                                _Float16* __restrict__ dtql,
                                                float* __restrict__ Bm,
                                                float* __restrict__ Cm) {
    int idx = blockIdx.x * 256 + threadIdx.x;   // < 4*1024*112
    int dir = idx / (MROWS * 112);
    int rem = idx - dir * MROWS * 112;
    int row = rem / 112, col = rem - row * 112;
    size_t rbase = (size_t)dir * MROWS + row;
    if (col < 64) {
        float v = (col < 48) ? acc[rbase * 80 + col] : 0.f;
        _Float16 h = (_Float16)v;
        dtqh[rbase * 64 + col] = h;
        dtql[rbase * 64 + col] = (_Float16)(v - (float)h);
    } else if (col < 80) {
        Bm[rbase * 16 + (col - 64)] = acc[rbase * 80 + (col - 16)];
    } else {
        Cm[rbase * 16 + (col - 80)] = acc[rbase * 80 + (col - 16)];
    }
}

// delta: per dir (1024x64pad)*(1536x64pad)^T, epilogue softplus(.+dtb) -> fp32
__global__ __launch_bounds__(256) void k_delta_t(const _Float16* __restrict__ dtqh,
                                                 const _Float16* __restrict__ dtql,
                                                 const _Float16* __restrict__ dtwh,
                                                 const _Float16* __restrict__ dtwl,
                                                 const float* __restrict__ dtb,
                                                 float* __restrict__ delta) {
    __shared__ _Float16 smem[192 * 64];
    int row0 = blockIdx.x * 64, col0 = blockIdx.y * 128, dir = blockIdx.z;
    floatx4 acc[2][4] = {};
    const size_t abase = ((size_t)dir * MROWS + row0) * 64;
    const size_t bbase = ((size_t)dir * DI + col0) * 64;
    gemm_core<64, 128, 2, 2, 4>(dtqh + abase, dtql + abase, 64,
                                dtwh + bbase, dtwl + bbase, 64, 2, smem, acc);
    int lane = threadIdx.x & 63, wave = threadIdx.x >> 6;
    int cc = lane & 15, q = lane >> 4;
    int rbase = row0 + (wave >> 1) * 32, cbase = col0 + (wave & 1) * 64;
    #pragma unroll
    for (int i = 0; i < 2; ++i)
        #pragma unroll
        for (int j = 0; j < 4; ++j) {
            int col = cbase + j * 16 + cc;
            float bias = dtb[(size_t)dir * DI + col];
            #pragma unroll
            for (int r = 0; r < 4; ++r) {
                float v = acc[i][j][r] + bias;
                float sp = (v > 20.f) ? v : log1pf(__expf(v));
                delta[((size_t)dir * MROWS + rbase + i * 16 + q * 4 + r) * DI + col] = sp;
            }
        }
}

// ---------------------------------------------------------------------------
// Depthwise causal conv (K=4) + bias + silu on permuted xz x-part,
// output split to hi/lo fp16 [dir][b*256+l_scan][D].
__global__ __launch_bounds__(256) void k_conv(const float* __restrict__ xz,
                                              const float* __restrict__ cw,
                                              const float* __restrict__ cb,
                                              _Float16* __restrict__ xh,
                                              _Float16* __restrict__ xl) {
    int dir = blockIdx.z;
    int bl = blockIdx.x;
    int b = bl >> 8, l = bl & 255;
    int d = blockIdx.y * 256 + threadIdx.x;
    const float* w = cw + ((size_t)dir * DI + d) * KI;
    float s = cb[(size_t)dir * DI + d];
    #pragma unroll
    for (int k = 0; k < KI; ++k) {
        int m = l - 3 + k;
        if (m >= 0) {
            int src = perm_idx(dir, m);
            s += w[k] * xz[((size_t)b * 256 + src) * F2D + d];
        }
    }
    float x = s / (1.f + __expf(-s));
    _Float16 h = (_Float16)x;
    size_t o = ((size_t)dir * MROWS + bl) * DI + d;
    xh[o] = h;
    xl[o] = (_Float16)(x - (float)h);
}

// ---------------------------------------------------------------------------
// Selective scan, software-pipelined. Block = 256 thr = 16(n) x 16(d-slot),
// one (dir,b,16 d's) per block. 32-step chunks, double-buffered LDS with
// interleaved (delta,x) and (B,C) pairs -> ds_read_b64 in the inner loop.
// Chunk c+1 operands prefetched into registers during chunk c's compute.
// ---------------------------------------------------------------------------
__global__ __launch_bounds__(256) void k_scan(const float* __restrict__ delta,
                                              const _Float16* __restrict__ xhg,
                                              const _Float16* __restrict__ xlg,
                                              const float* __restrict__ xz,
                                              const float* __restrict__ Bm,
                                              const float* __restrict__ Cm,
                                              const float* __restrict__ A_log,
                                              const float* __restrict__ Dp,
                                              float* __restrict__ ydir) {
    const int dblock = blockIdx.x, b = blockIdx.y, dir = blockIdx.z;
    const int tid = threadIdx.x;
    const int n = tid & 15, ds = (tid >> 4) & 15;
    const int d = dblock * 16 + ds;

    __shared__ float sdx[2][32][32];   // [buf][jj][ds*2 + {0:delta,1:x}]
    __shared__ float sbc[2][32][32];   // [buf][jj][n*2  + {0:B,1:C}]
    __shared__ float sY[32][16];

    const float Aval = -__expf(A_log[((size_t)dir * DI + d) * NI + n]);
    const float Dpar = Dp[(size_t)dir * DI + d];
    float h = 0.f;

    const size_t dirrow = (size_t)dir * MROWS;
    // staging/write-phase roles: rows sjj = tid>>3 (0..31), col pair sc0
    const int sjj = tid >> 3, sc0 = (tid & 7) * 2;

    float r_d0, r_d1, r_x0, r_x1, r_b0, r_b1, r_c0, r_c1, r_z0, r_z1;
    auto load_chunk = [&](int j0) {
        int row = b * 256 + j0 + sjj;
        size_t o = (dirrow + row) * DI + dblock * 16 + sc0;
        floatx2 dv = *(const floatx2*)(delta + o);
        halfx2 hx = *(const halfx2*)(xhg + o);
        halfx2 lx = *(const halfx2*)(xlg + o);
        floatx2 bv = *(const floatx2*)(Bm + (dirrow + row) * 16 + sc0);
        floatx2 cv = *(const floatx2*)(Cm + (dirrow + row) * 16 + sc0);
        int lsrc = perm_idx(dir, j0 + sjj);
        floatx2 zv = *(const floatx2*)(xz + ((size_t)b * 256 + lsrc) * F2D + DI + dblock * 16 + sc0);
        r_d0 = dv[0]; r_d1 = dv[1];
        r_x0 = (float)hx[0] + (float)lx[0];
        r_x1 = (float)hx[1] + (float)lx[1];
        r_b0 = bv[0]; r_b1 = bv[1];
        r_c0 = cv[0]; r_c1 = cv[1];
        r_z0 = zv[0]; r_z1 = zv[1];
    };

    load_chunk(0);

    for (int c = 0; c < 8; ++c) {
        const int buf = c & 1;
        // stage chunk c from regs into LDS (interleaved pairs, b128 writes)
        {
            floatx4 wdx = {r_d0, r_x0, r_d1, r_x1};
            floatx4 wbc = {r_b0, r_c0, r_b1, r_c1};
            *(floatx4*)&sdx[buf][sjj][sc0 * 2] = wdx;
            *(floatx4*)&sbc[buf][sjj][sc0 * 2] = wbc;
        }
        // keep z for this chunk's write phase before prefetch clobbers regs
        float z0 = r_z0, z1 = r_z1;
        __syncthreads();                 // LDS chunk c visible; sY free
        if (c < 7) load_chunk((c + 1) * 32);   // prefetch, no wait

        // ---- 32 recurrence steps ----
        #pragma unroll
        for (int jj = 0; jj < 32; ++jj) {
            floatx2 dx = *(const floatx2*)&sdx[buf][jj][ds * 2];
            floatx2 bc = *(const floatx2*)&sbc[buf][jj][n * 2];
            float dv = dx[0], xv = dx[1];
            float a  = __expf(dv * Aval);
            h = fmaf(a, h, dv * xv * bc[0]);
            float p = h * bc[1];
            p += __shfl_xor(p, 1);
            p += __shfl_xor(p, 2);
            p += __shfl_xor(p, 4);
            p += __shfl_xor(p, 8);
            if (n == 0) sY[jj][ds] = fmaf(Dpar, xv, p);
        }
        __syncthreads();                 // sY complete

        // ---- gated write to out-domain (2 floats/thread, coalesced) ----
        {
            int lout = perm_idx(dir, c * 32 + sjj);
            float y0 = sY[sjj][sc0], y1 = sY[sjj][sc0 + 1];
            float g0 = z0 / (1.f + __expf(-z0));
            float g1 = z1 / (1.f + __expf(-z1));
            floatx2 o = {y0 * g0, y1 * g1};
            *(floatx2*)&ydir[(dirrow + (size_t)b * 256 + lout) * DI + dblock * 16 + sc0] = o;
        }
    }
}

// sum of 4 direction outputs -> hi/lo fp16 for out_proj A-operand
__global__ __launch_bounds__(256) void k_sum(const float* __restrict__ ydir,
                                             _Float16* __restrict__ yh,
                                             _Float16* __restrict__ yl) {
    int i = blockIdx.x * 256 + threadIdx.x;
    const size_t S = (size_t)MROWS * DI;
    float s = ydir[i] + ydir[S + i] + ydir[2 * S + i] + ydir[3 * S + i];
    _Float16 h = (_Float16)s;
    yh[i] = h;
    yl[i] = (_Float16)(s - (float)h);
}

// ---------------------------------------------------------------------------
extern "C" void kernel_launch(void* const* d_in, const int* in_sizes, int n_in,
                              void* d_out, int out_size, void* d_ws, size_t ws_size,
                              hipStream_t stream) {
    const float* hs   = (const float*)d_in[0];
    const float* wip  = (const float*)d_in[1];
    const float* wop  = (const float*)d_in[2];
    const float* cw   = (const float*)d_in[3];
    const float* cb   = (const float*)d_in[4];
    const float* xw   = (const float*)d_in[5];
    const float* dtw  = (const float*)d_in[6];
    const float* dtb  = (const float*)d_in[7];
    const float* alog = (const float*)d_in[8];
    const float* dpar = (const float*)d_in[9];
    float* out = (float*)d_out;

    char* p = (char*)d_ws;
    auto alloc_f32 = [&](size_t n) { float* r = (float*)p; p += n * 4; return r; };
    auto alloc_f16 = [&](size_t n) { _Float16* r = (_Float16*)p; p += n * 2; return r; };

    _Float16* hsh  = alloc_f16(786432);
    _Float16* hsl  = alloc_f16(786432);
    _Float16* wiph = alloc_f16(2359296);
    _Float16* wipl = alloc_f16(2359296);
    _Float16* woph = alloc_f16(1179648);
    _Float16* wopl = alloc_f16(1179648);
    _Float16* xwh  = alloc_f16(491520);
    _Float16* xwl  = alloc_f16(491520);
    _Float16* dtwh = alloc_f16((size_t)NDIRS * DI * 64);
    _Float16* dtwl = alloc_f16((size_t)NDIRS * DI * 64);
    float*    xz   = alloc_f32((size_t)MROWS * F2D);
    _Float16* xh   = alloc_f16((size_t)NDIRS * MROWS * DI);
    _Float16* xl   = alloc_f16((size_t)NDIRS * MROWS * DI);
    float*    xdba = alloc_f32((size_t)NDIRS * MROWS * 80);
    _Float16* dtqh = alloc_f16((size_t)NDIRS * MROWS * 64);
    _Float16* dtql = alloc_f16((size_t)NDIRS * MROWS * 64);
    float*    Bmb  = alloc_f32((size_t)NDIRS * MROWS * 16);
    float*    Cmb  = alloc_f32((size_t)NDIRS * MROWS * 16);
    float*    delta= alloc_f32((size_t)NDIRS * MROWS * DI);
    float*    ydir = alloc_f32((size_t)NDIRS * MROWS * DI);
    _Float16* yh   = alloc_f16((size_t)MROWS * DI);
    _Float16* yl   = alloc_f16((size_t)MROWS * DI);

    k_zero    <<<dim3(1280), 256, 0, stream>>>(xdba, NDIRS * MROWS * 80);
    k_zero    <<<dim3(3072), 256, 0, stream>>>(out, MROWS * EI);
    k_splitall<<<dim3(20352), 256, 0, stream>>>(hs, wip, wop, xw, dtw,
                                                hsh, hsl, wiph, wipl, woph, wopl,
                                                xwh, xwl, dtwh, dtwl);
    k_inproj_t<<<dim3(16, 24), 256, 0, stream>>>(hsh, hsl, wiph, wipl, xz);
    k_conv    <<<dim3(MROWS, DI / 256, NDIRS), 256, 0, stream>>>(xz, cw, cb, xh, xl);
    k_xdbl_t  <<<dim3(8, NDIRS, 8), 256, 0, stream>>>(xh, xl, xwh, xwl, xdba);
    k_xsplit  <<<dim3(1792), 256, 0, stream>>>(xdba, dtqh, dtql, Bmb, Cmb);
    k_delta_t <<<dim3(16, 12, NDIRS), 256, 0, stream>>>(dtqh, dtql, dtwh, dtwl, dtb, delta);
    k_scan    <<<dim3(DI / 16, BI, NDIRS), 256, 0, stream>>>(delta, xh, xl, xz, Bmb, Cmb,
                                                             alog, dpar, ydir);
    k_sum     <<<dim3((MROWS * DI) / 256), 256, 0, stream>>>(ydir, yh, yl);
    k_outproj_t<<<dim3(16, 6, 4), 256, 0, stream>>>(yh, yl, woph, wopl, out);
}

// Round 5
// 281.148 us; speedup vs baseline: 1.7908x; 1.1910x over previous
//
#include <hip/hip_runtime.h>
#include <hip/hip_bf16.h>

#define BI   4
#define LI   256
#define EI   768
#define DI   1536
#define NI   16
#define RI   48
#define KI   4
#define NDIRS 4
#define F2D  3072              // 2*D
#define MROWS 1024             // B*L

typedef float    floatx2 __attribute__((ext_vector_type(2)));
typedef float    floatx4 __attribute__((ext_vector_type(4)));
typedef _Float16 halfx2  __attribute__((ext_vector_type(2)));
typedef _Float16 halfx8  __attribute__((ext_vector_type(8)));

typedef __attribute__((address_space(3))) unsigned lds_u32;
typedef __attribute__((address_space(1))) const unsigned glb_u32;

__device__ __forceinline__ void load16(const _Float16* g, _Float16* l) {
    __builtin_amdgcn_global_load_lds((glb_u32*)g, (lds_u32*)l, 16, 0, 0);
}

__device__ __forceinline__ int perm_idx(int dir, int j) {
    switch (dir) {
        case 0:  return j;
        case 1:  return 255 - j;
        case 2:  return ((j & 15) << 4) | (j >> 4);
        default: return 255 - (((j & 15) << 4) | (j >> 4));
    }
}

// DPP-based add of a permuted copy (VALU pipe, no LDS traffic).
template<int CTRL>
__device__ __forceinline__ float dpp_add(float p) {
    int t = __builtin_amdgcn_update_dpp(0, __builtin_bit_cast(int, p),
                                        CTRL, 0xf, 0xf, true);
    return p + __builtin_bit_cast(float, t);
}
// sum over the 16 lanes of a DPP row (n = lane & 15)
__device__ __forceinline__ float row16_sum(float p) {
    p = dpp_add<0xB1>(p);    // quad_perm [1,0,3,2]  : xor 1
    p = dpp_add<0x4E>(p);    // quad_perm [2,3,0,1]  : xor 2
    p = dpp_add<0x141>(p);   // row_half_mirror      : combine quads
    p = dpp_add<0x140>(p);   // row_mirror           : combine halves
    return p;
}

// ---------------------------------------------------------------------------
// Tiled hi/lo-fp16 GEMM core. C[M,N] = A[M,K]*B[N,K]^T with A,B pre-split to
// hi/lo fp16 (a = ah + al, |al| <= 2^-11|a|). 4 waves/block, wave grid
// (4/WGN) x WGN, fragment grid FM x FN of 16x16 tiles. LDS tiles [rows][32]
// fp16, unpadded (global_load_lds lane-order requirement). K consumed in
// chunks of 32. acc += ah*bh + ah*bl + al*bh  (al*bl term ~2^-22, dropped).
// ---------------------------------------------------------------------------
template<int BM, int BN, int WGN, int FM, int FN>
__device__ __forceinline__ void gemm_core(const _Float16* __restrict__ Ah,
                                          const _Float16* __restrict__ Al, int lda,
                                          const _Float16* __restrict__ Bh,
                                          const _Float16* __restrict__ Bl, int ldb,
                                          int nChunks, _Float16* smem,
                                          floatx4 (&acc)[FM][FN]) {
    const int tid = threadIdx.x, lane = tid & 63, wave = tid >> 6;
    const int wave_m = wave / WGN, wave_n = wave % WGN;
    _Float16* sAh = smem;
    _Float16* sAl = smem + BM * 32;
    _Float16* sBh = smem + BM * 64;
    _Float16* sBl = smem + BM * 64 + BN * 32;
    const int rr = lane & 15, koff = (lane >> 4) * 8;
    const int arow = wave_m * FM * 16, brow = wave_n * FN * 16;

    for (int c = 0; c < nChunks; ++c) {
        for (int idx = tid; idx < BM * 4; idx += 256) {
            int r = idx >> 2, s = (idx & 3) * 8;
            load16(Ah + (size_t)r * lda + c * 32 + s, sAh + idx * 8);
            load16(Al + (size_t)r * lda + c * 32 + s, sAl + idx * 8);
        }
        for (int idx = tid; idx < BN * 4; idx += 256) {
            int r = idx >> 2, s = (idx & 3) * 8;
            load16(Bh + (size_t)r * ldb + c * 32 + s, sBh + idx * 8);
            load16(Bl + (size_t)r * ldb + c * 32 + s, sBl + idx * 8);
        }
        asm volatile("s_waitcnt vmcnt(0)" ::: "memory");
        __syncthreads();

        halfx8 ahf[FM], alf[FM], bhf[FN], blf[FN];
        #pragma unroll
        for (int i = 0; i < FM; ++i) {
            ahf[i] = *(const halfx8*)(sAh + (arow + i * 16 + rr) * 32 + koff);
            alf[i] = *(const halfx8*)(sAl + (arow + i * 16 + rr) * 32 + koff);
        }
        #pragma unroll
        for (int j = 0; j < FN; ++j) {
            bhf[j] = *(const halfx8*)(sBh + (brow + j * 16 + rr) * 32 + koff);
            blf[j] = *(const halfx8*)(sBl + (brow + j * 16 + rr) * 32 + koff);
        }
        #pragma unroll
        for (int i = 0; i < FM; ++i)
            #pragma unroll
            for (int j = 0; j < FN; ++j) {
                acc[i][j] = __builtin_amdgcn_mfma_f32_16x16x32_f16(ahf[i], bhf[j], acc[i][j], 0, 0, 0);
                acc[i][j] = __builtin_amdgcn_mfma_f32_16x16x32_f16(ahf[i], blf[j], acc[i][j], 0, 0, 0);
                acc[i][j] = __builtin_amdgcn_mfma_f32_16x16x32_f16(alf[i], bhf[j], acc[i][j], 0, 0, 0);
            }
        __syncthreads();
    }
}

// ---------------------------------------------------------------------------
__global__ __launch_bounds__(256) void k_zero(float* __restrict__ a, int n) {
    int i = blockIdx.x * 256 + threadIdx.x;
    if (i < n) a[i] = 0.f;
}

// split all static operands to hi/lo fp16 (dtw also padded K 48->64)
__global__ __launch_bounds__(256) void k_splitall(
        const float* __restrict__ hs,  const float* __restrict__ wip,
        const float* __restrict__ wop, const float* __restrict__ xw,
        const float* __restrict__ dtw,
        _Float16* __restrict__ hsh,  _Float16* __restrict__ hsl,
        _Float16* __restrict__ wiph, _Float16* __restrict__ wipl,
        _Float16* __restrict__ woph, _Float16* __restrict__ wopl,
        _Float16* __restrict__ xwh,  _Float16* __restrict__ xwl,
        _Float16* __restrict__ dtwh, _Float16* __restrict__ dtwl) {
    int idx = blockIdx.x * 256 + threadIdx.x;
    float v; _Float16 *dh, *dl; int off;
    if (idx < 786432)        { off = idx;           v = hs[off];  dh = hsh;  dl = hsl;  }
    else if (idx < 3145728)  { off = idx - 786432;  v = wip[off]; dh = wiph; dl = wipl; }
    else if (idx < 4325376)  { off = idx - 3145728; v = wop[off]; dh = woph; dl = wopl; }
    else if (idx < 4816896)  { off = idx - 4325376; v = xw[off];  dh = xwh;  dl = xwl;  }
    else {
        int t = idx - 4816896;          // [dir*1536 + d][64] padded
        int col = t & 63, dr = t >> 6;
        v = (col < 48) ? dtw[(size_t)dr * 48 + col] : 0.f;
        _Float16 h = (_Float16)v;
        dtwh[t] = h; dtwl[t] = (_Float16)(v - (float)h);
        return;
    }
    _Float16 h = (_Float16)v;
    dh[off] = h; dl[off] = (_Float16)(v - (float)h);
}

// ---------------------------------------------------------------------------
// in_proj: (1024x768)*(3072x768)^T -> xz fp32 (1024x3072)
__global__ __launch_bounds__(256) void k_inproj_t(const _Float16* __restrict__ Ah,
                                                  const _Float16* __restrict__ Al,
                                                  const _Float16* __restrict__ Bh,
                                                  const _Float16* __restrict__ Bl,
                                                  float* __restrict__ C) {
    __shared__ _Float16 smem[192 * 64];
    int row0 = blockIdx.x * 64, col0 = blockIdx.y * 128;
    floatx4 acc[2][4] = {};
    gemm_core<64, 128, 2, 2, 4>(Ah + (size_t)row0 * EI, Al + (size_t)row0 * EI, EI,
                                Bh + (size_t)col0 * EI, Bl + (size_t)col0 * EI, EI,
                                EI / 32, smem, acc);
    int lane = threadIdx.x & 63, wave = threadIdx.x >> 6;
    int cc = lane & 15, q = lane >> 4;
    int rbase = row0 + (wave >> 1) * 32, cbase = col0 + (wave & 1) * 64;
    #pragma unroll
    for (int i = 0; i < 2; ++i)
        #pragma unroll
        for (int j = 0; j < 4; ++j)
            #pragma unroll
            for (int r = 0; r < 4; ++r)
                C[(size_t)(rbase + i * 16 + q * 4 + r) * F2D + cbase + j * 16 + cc] = acc[i][j][r];
}

// out_proj: (1024x1536)*(768x1536)^T -> out fp32 (1024x768), K-split x4 + atomic
__global__ __launch_bounds__(256) void k_outproj_t(const _Float16* __restrict__ Ah,
                                                   const _Float16* __restrict__ Al,
                                                   const _Float16* __restrict__ Bh,
                                                   const _Float16* __restrict__ Bl,
                                                   float* __restrict__ C) {
    __shared__ _Float16 smem[192 * 64];
    int row0 = blockIdx.x * 64, col0 = blockIdx.y * 128, k0 = blockIdx.z * 384;
    floatx4 acc[2][4] = {};
    gemm_core<64, 128, 2, 2, 4>(Ah + (size_t)row0 * DI + k0, Al + (size_t)row0 * DI + k0, DI,
                                Bh + (size_t)col0 * DI + k0, Bl + (size_t)col0 * DI + k0, DI,
                                12, smem, acc);
    int lane = threadIdx.x & 63, wave = threadIdx.x >> 6;
    int cc = lane & 15, q = lane >> 4;
    int rbase = row0 + (wave >> 1) * 32, cbase = col0 + (wave & 1) * 64;
    #pragma unroll
    for (int i = 0; i < 2; ++i)
        #pragma unroll
        for (int j = 0; j < 4; ++j)
            #pragma unroll
            for (int r = 0; r < 4; ++r)
                atomicAdd(&C[(size_t)(rbase + i * 16 + q * 4 + r) * EI + cbase + j * 16 + cc], acc[i][j][r]);
}

// x_dbl: per dir (1024x1536)*(80x1536)^T -> xdbl_acc fp32, K-split x8 + atomic
__global__ __launch_bounds__(256) void k_xdbl_t(const _Float16* __restrict__ xh,
                                                const _Float16* __restrict__ xl,
                                                const _Float16* __restrict__ xwh,
                                                const _Float16* __restrict__ xwl,
                                                float* __restrict__ C) {
    __shared__ _Float16 smem[208 * 64];
    int row0 = blockIdx.x * 128, dir = blockIdx.y, k0 = blockIdx.z * 192;
    floatx4 acc[2][5] = {};
    const size_t abase = ((size_t)dir * MROWS + row0) * DI + k0;
    const size_t bbase = (size_t)dir * 80 * DI + k0;
    gemm_core<128, 80, 1, 2, 5>(xh + abase, xl + abase, DI,
                                xwh + bbase, xwl + bbase, DI, 6, smem, acc);
    int lane = threadIdx.x & 63, wave = threadIdx.x >> 6;
    int cc = lane & 15, q = lane >> 4;
    int rbase = row0 + wave * 32;
    #pragma unroll
    for (int i = 0; i < 2; ++i)
        #pragma unroll
        for (int j = 0; j < 5; ++j)
            #pragma unroll
            for (int r = 0; r < 4; ++r)
                atomicAdd(&C[((size_t)dir * MROWS + rbase + i * 16 + q * 4 + r) * 80 + j * 16 + cc],
                          acc[i][j][r]);
}

// xdbl epilogue: split cols -> dtq hi/lo (padded to 64), Bm, Cm fp32
__global__ __launch_bounds__(256) void k_xsplit(const float* __restrict__ acc,
                                                _Float16* __restrict__ dtqh,
                                                _Float16* __restrict__ dtql,
                                                float* __restrict__ Bm,
                                                float* __restrict__ Cm) {
    int idx = blockIdx.x * 256 + threadIdx.x;   // < 4*1024*112
    int dir = idx / (MROWS * 112);
    int rem = idx - dir * MROWS * 112;
    int row = rem / 112, col = rem - row * 112;
    size_t rbase = (size_t)dir * MROWS + row;
    if (col < 64) {
        float v = (col < 48) ? acc[rbase * 80 + col] : 0.f;
        _Float16 h = (_Float16)v;
        dtqh[rbase * 64 + col] = h;
        dtql[rbase * 64 + col] = (_Float16)(v - (float)h);
    } else if (col < 80) {
        Bm[rbase * 16 + (col - 64)] = acc[rbase * 80 + (col - 16)];
    } else {
        Cm[rbase * 16 + (col - 80)] = acc[rbase * 80 + (col - 16)];
    }
}

// delta: per dir (1024x64pad)*(1536x64pad)^T, epilogue softplus(.+dtb) -> fp32
__global__ __launch_bounds__(256) void k_delta_t(const _Float16* __restrict__ dtqh,
                                                 const _Float16* __restrict__ dtql,
                                                 const _Float16* __restrict__ dtwh,
                                                 const _Float16* __restrict__ dtwl,
                                                 const float* __restrict__ dtb,
                                                 float* __restrict__ delta) {
    __shared__ _Float16 smem[192 * 64];
    int row0 = blockIdx.x * 64, col0 = blockIdx.y * 128, dir = blockIdx.z;
    floatx4 acc[2][4] = {};
    const size_t abase = ((size_t)dir * MROWS + row0) * 64;
    const size_t bbase = ((size_t)dir * DI + col0) * 64;
    gemm_core<64, 128, 2, 2, 4>(dtqh + abase, dtql + abase, 64,
                                dtwh + bbase, dtwl + bbase, 64, 2, smem, acc);
    int lane = threadIdx.x & 63, wave = threadIdx.x >> 6;
    int cc = lane & 15, q = lane >> 4;
    int rbase = row0 + (wave >> 1) * 32, cbase = col0 + (wave & 1) * 64;
    #pragma unroll
    for (int i = 0; i < 2; ++i)
        #pragma unroll
        for (int j = 0; j < 4; ++j) {
            int col = cbase + j * 16 + cc;
            float bias = dtb[(size_t)dir * DI + col];
            #pragma unroll
            for (int r = 0; r < 4; ++r) {
                float v = acc[i][j][r] + bias;
                float sp = (v > 20.f) ? v : log1pf(__expf(v));
                delta[((size_t)dir * MROWS + rbase + i * 16 + q * 4 + r) * DI + col] = sp;
            }
        }
}

// ---------------------------------------------------------------------------
// Depthwise causal conv (K=4) + bias + silu on permuted xz x-part,
// output split to hi/lo fp16 [dir][b*256+l_scan][D].
__global__ __launch_bounds__(256) void k_conv(const float* __restrict__ xz,
                                              const float* __restrict__ cw,
                                              const float* __restrict__ cb,
                                              _Float16* __restrict__ xh,
                                              _Float16* __restrict__ xl) {
    int dir = blockIdx.z;
    int bl = blockIdx.x;
    int b = bl >> 8, l = bl & 255;
    int d = blockIdx.y * 256 + threadIdx.x;
    const float* w = cw + ((size_t)dir * DI + d) * KI;
    float s = cb[(size_t)dir * DI + d];
    #pragma unroll
    for (int k = 0; k < KI; ++k) {
        int m = l - 3 + k;
        if (m >= 0) {
            int src = perm_idx(dir, m);
            s += w[k] * xz[((size_t)b * 256 + src) * F2D + d];
        }
    }
    float x = s / (1.f + __expf(-s));
    _Float16 h = (_Float16)x;
    size_t o = ((size_t)dir * MROWS + bl) * DI + d;
    xh[o] = h;
    xl[o] = (_Float16)(x - (float)h);
}

// ---------------------------------------------------------------------------
// Selective scan, software-pipelined, DPP reduction (no LDS shuffles).
// Block = 256 thr = 16(n) x 16(d-slot), one (dir,b,16 d's) per block.
// 32-step chunks, double-buffered LDS, (delta,x) and (B,C) interleaved pairs
// -> 2 broadcast ds_read_b64 per step; n-reduction entirely on VALU via DPP.
// ---------------------------------------------------------------------------
__global__ __launch_bounds__(256) void k_scan(const float* __restrict__ delta,
                                              const _Float16* __restrict__ xhg,
                                              const _Float16* __restrict__ xlg,
                                              const float* __restrict__ xz,
                                              const float* __restrict__ Bm,
                                              const float* __restrict__ Cm,
                                              const float* __restrict__ A_log,
                                              const float* __restrict__ Dp,
                                              float* __restrict__ ydir) {
    const int dblock = blockIdx.x, b = blockIdx.y, dir = blockIdx.z;
    const int tid = threadIdx.x;
    const int n = tid & 15, ds = (tid >> 4) & 15;
    const int d = dblock * 16 + ds;

    __shared__ float sdx[2][32][32];   // [buf][jj][ds*2 + {0:delta,1:x}]
    __shared__ float sbc[2][32][32];   // [buf][jj][n*2  + {0:B,1:C}]
    __shared__ float sY[32][16];

    const float Aval = -__expf(A_log[((size_t)dir * DI + d) * NI + n]);
    const float Dpar = Dp[(size_t)dir * DI + d];
    float h = 0.f;

    const size_t dirrow = (size_t)dir * MROWS;
    const int sjj = tid >> 3, sc0 = (tid & 7) * 2;

    float r_d0, r_d1, r_x0, r_x1, r_b0, r_b1, r_c0, r_c1, r_z0, r_z1;
    auto load_chunk = [&](int j0) {
        int row = b * 256 + j0 + sjj;
        size_t o = (dirrow + row) * DI + dblock * 16 + sc0;
        floatx2 dv = *(const floatx2*)(delta + o);
        halfx2 hx = *(const halfx2*)(xhg + o);
        halfx2 lx = *(const halfx2*)(xlg + o);
        floatx2 bv = *(const floatx2*)(Bm + (dirrow + row) * 16 + sc0);
        floatx2 cv = *(const floatx2*)(Cm + (dirrow + row) * 16 + sc0);
        int lsrc = perm_idx(dir, j0 + sjj);
        floatx2 zv = *(const floatx2*)(xz + ((size_t)b * 256 + lsrc) * F2D + DI + dblock * 16 + sc0);
        r_d0 = dv[0]; r_d1 = dv[1];
        r_x0 = (float)hx[0] + (float)lx[0];
        r_x1 = (float)hx[1] + (float)lx[1];
        r_b0 = bv[0]; r_b1 = bv[1];
        r_c0 = cv[0]; r_c1 = cv[1];
        r_z0 = zv[0]; r_z1 = zv[1];
    };

    load_chunk(0);

    for (int c = 0; c < 8; ++c) {
        const int buf = c & 1;
        {
            floatx4 wdx = {r_d0, r_x0, r_d1, r_x1};
            floatx4 wbc = {r_b0, r_c0, r_b1, r_c1};
            *(floatx4*)&sdx[buf][sjj][sc0 * 2] = wdx;
            *(floatx4*)&sbc[buf][sjj][sc0 * 2] = wbc;
        }
        float z0 = r_z0, z1 = r_z1;
        __syncthreads();                 // LDS chunk c visible; sY free
        if (c < 7) load_chunk((c + 1) * 32);   // prefetch, no wait

        // ---- 32 recurrence steps, DPP reduction over n ----
        #pragma unroll
        for (int jj = 0; jj < 32; ++jj) {
            floatx2 dx = *(const floatx2*)&sdx[buf][jj][ds * 2];
            floatx2 bc = *(const floatx2*)&sbc[buf][jj][n * 2];
            float dv = dx[0], xv = dx[1];
            float a  = __expf(dv * Aval);
            h = fmaf(a, h, dv * xv * bc[0]);
            float p = row16_sum(h * bc[1]);
            if (n == 0) sY[jj][ds] = fmaf(Dpar, xv, p);
        }
        __syncthreads();                 // sY complete

        // ---- gated write to out-domain (2 floats/thread, coalesced) ----
        {
            int lout = perm_idx(dir, c * 32 + sjj);
            float y0 = sY[sjj][sc0], y1 = sY[sjj][sc0 + 1];
            float g0 = z0 / (1.f + __expf(-z0));
            float g1 = z1 / (1.f + __expf(-z1));
            floatx2 o = {y0 * g0, y1 * g1};
            *(floatx2*)&ydir[(dirrow + (size_t)b * 256 + lout) * DI + dblock * 16 + sc0] = o;
        }
    }
}

// sum of 4 direction outputs -> hi/lo fp16 for out_proj A-operand
__global__ __launch_bounds__(256) void k_sum(const float* __restrict__ ydir,
                                             _Float16* __restrict__ yh,
                                             _Float16* __restrict__ yl) {
    int i = blockIdx.x * 256 + threadIdx.x;
    const size_t S = (size_t)MROWS * DI;
    float s = ydir[i] + ydir[S + i] + ydir[2 * S + i] + ydir[3 * S + i];
    _Float16 h = (_Float16)s;
    yh[i] = h;
    yl[i] = (_Float16)(s - (float)h);
}

// ---------------------------------------------------------------------------
extern "C" void kernel_launch(void* const* d_in, const int* in_sizes, int n_in,
                              void* d_out, int out_size, void* d_ws, size_t ws_size,
                              hipStream_t stream) {
    const float* hs   = (const float*)d_in[0];
    const float* wip  = (const float*)d_in[1];
    const float* wop  = (const float*)d_in[2];
    const float* cw   = (const float*)d_in[3];
    const float* cb   = (const float*)d_in[4];
    const float* xw   = (const float*)d_in[5];
    const float* dtw  = (const float*)d_in[6];
    const float* dtb  = (const float*)d_in[7];
    const float* alog = (const float*)d_in[8];
    const float* dpar = (const float*)d_in[9];
    float* out = (float*)d_out;

    char* p = (char*)d_ws;
    auto alloc_f32 = [&](size_t n) { float* r = (float*)p; p += n * 4; return r; };
    auto alloc_f16 = [&](size_t n) { _Float16* r = (_Float16*)p; p += n * 2; return r; };

    _Float16* hsh  = alloc_f16(786432);
    _Float16* hsl  = alloc_f16(786432);
    _Float16* wiph = alloc_f16(2359296);
    _Float16* wipl = alloc_f16(2359296);
    _Float16* woph = alloc_f16(1179648);
    _Float16* wopl = alloc_f16(1179648);
    _Float16* xwh  = alloc_f16(491520);
    _Float16* xwl  = alloc_f16(491520);
    _Float16* dtwh = alloc_f16((size_t)NDIRS * DI * 64);
    _Float16* dtwl = alloc_f16((size_t)NDIRS * DI * 64);
    float*    xz   = alloc_f32((size_t)MROWS * F2D);
    _Float16* xh   = alloc_f16((size_t)NDIRS * MROWS * DI);
    _Float16* xl   = alloc_f16((size_t)NDIRS * MROWS * DI);
    float*    xdba = alloc_f32((size_t)NDIRS * MROWS * 80);
    _Float16* dtqh = alloc_f16((size_t)NDIRS * MROWS * 64);
    _Float16* dtql = alloc_f16((size_t)NDIRS * MROWS * 64);
    float*    Bmb  = alloc_f32((size_t)NDIRS * MROWS * 16);
    float*    Cmb  = alloc_f32((size_t)NDIRS * MROWS * 16);
    float*    delta= alloc_f32((size_t)NDIRS * MROWS * DI);
    float*    ydir = alloc_f32((size_t)NDIRS * MROWS * DI);
    _Float16* yh   = alloc_f16((size_t)MROWS * DI);
    _Float16* yl   = alloc_f16((size_t)MROWS * DI);

    k_zero    <<<dim3(1280), 256, 0, stream>>>(xdba, NDIRS * MROWS * 80);
    k_zero    <<<dim3(3072), 256, 0, stream>>>(out, MROWS * EI);
    k_splitall<<<dim3(20352), 256, 0, stream>>>(hs, wip, wop, xw, dtw,
                                                hsh, hsl, wiph, wipl, woph, wopl,
                                                xwh, xwl, dtwh, dtwl);
    k_inproj_t<<<dim3(16, 24), 256, 0, stream>>>(hsh, hsl, wiph, wipl, xz);
    k_conv    <<<dim3(MROWS, DI / 256, NDIRS), 256, 0, stream>>>(xz, cw, cb, xh, xl);
    k_xdbl_t  <<<dim3(8, NDIRS, 8), 256, 0, stream>>>(xh, xl, xwh, xwl, xdba);
    k_xsplit  <<<dim3(1792), 256, 0, stream>>>(xdba, dtqh, dtql, Bmb, Cmb);
    k_delta_t <<<dim3(16, 12, NDIRS), 256, 0, stream>>>(dtqh, dtql, dtwh, dtwl, dtb, delta);
    k_scan    <<<dim3(DI / 16, BI, NDIRS), 256, 0, stream>>>(delta, xh, xl, xz, Bmb, Cmb,
                                                             alog, dpar, ydir);
    k_sum     <<<dim3((MROWS * DI) / 256), 256, 0, stream>>>(ydir, yh, yl);
    k_outproj_t<<<dim3(16, 6, 4), 256, 0, stream>>>(yh, yl, woph, wopl, out);
}

// Round 6
// 270.176 us; speedup vs baseline: 1.8635x; 1.0406x over previous
//
#include <hip/hip_runtime.h>
#include <hip/hip_bf16.h>

#define BI   4
#define LI   256
#define EI   768
#define DI   1536
#define NI   16
#define RI   48
#define KI   4
#define NDIRS 4
#define F2D  3072              // 2*D
#define MROWS 1024             // B*L

typedef float    floatx2 __attribute__((ext_vector_type(2)));
typedef float    floatx4 __attribute__((ext_vector_type(4)));
typedef _Float16 halfx2  __attribute__((ext_vector_type(2)));
typedef _Float16 halfx4  __attribute__((ext_vector_type(4)));
typedef _Float16 halfx8  __attribute__((ext_vector_type(8)));

typedef __attribute__((address_space(3))) unsigned lds_u32;
typedef __attribute__((address_space(1))) const unsigned glb_u32;

__device__ __forceinline__ void load16(const _Float16* g, _Float16* l) {
    __builtin_amdgcn_global_load_lds((glb_u32*)g, (lds_u32*)l, 16, 0, 0);
}

__device__ __forceinline__ int perm_idx(int dir, int j) {
    switch (dir) {
        case 0:  return j;
        case 1:  return 255 - j;
        case 2:  return ((j & 15) << 4) | (j >> 4);
        default: return 255 - (((j & 15) << 4) | (j >> 4));
    }
}

// DPP-based add of a permuted copy (VALU pipe, no LDS traffic).
template<int CTRL>
__device__ __forceinline__ float dpp_add(float p) {
    int t = __builtin_amdgcn_update_dpp(0, __builtin_bit_cast(int, p),
                                        CTRL, 0xf, 0xf, true);
    return p + __builtin_bit_cast(float, t);
}
// sum over 8 consecutive lanes (tid&7 group)
__device__ __forceinline__ float grp8_sum(float p) {
    p = dpp_add<0xB1>(p);    // quad_perm [1,0,3,2]  : xor 1
    p = dpp_add<0x4E>(p);    // quad_perm [2,3,0,1]  : xor 2
    p = dpp_add<0x141>(p);   // row_half_mirror      : combine quads
    return p;
}

// ---------------------------------------------------------------------------
// Tiled hi/lo-fp16 GEMM core (see round-3 notes). LDS tiles [rows][32] fp16,
// unpadded (global_load_lds lane-order). acc += ah*bh + ah*bl + al*bh.
// ---------------------------------------------------------------------------
template<int BM, int BN, int WGN, int FM, int FN>
__device__ __forceinline__ void gemm_core(const _Float16* __restrict__ Ah,
                                          const _Float16* __restrict__ Al, int lda,
                                          const _Float16* __restrict__ Bh,
                                          const _Float16* __restrict__ Bl, int ldb,
                                          int nChunks, _Float16* smem,
                                          floatx4 (&acc)[FM][FN]) {
    const int tid = threadIdx.x, lane = tid & 63, wave = tid >> 6;
    const int wave_m = wave / WGN, wave_n = wave % WGN;
    _Float16* sAh = smem;
    _Float16* sAl = smem + BM * 32;
    _Float16* sBh = smem + BM * 64;
    _Float16* sBl = smem + BM * 64 + BN * 32;
    const int rr = lane & 15, koff = (lane >> 4) * 8;
    const int arow = wave_m * FM * 16, brow = wave_n * FN * 16;

    for (int c = 0; c < nChunks; ++c) {
        for (int idx = tid; idx < BM * 4; idx += 256) {
            int r = idx >> 2, s = (idx & 3) * 8;
            load16(Ah + (size_t)r * lda + c * 32 + s, sAh + idx * 8);
            load16(Al + (size_t)r * lda + c * 32 + s, sAl + idx * 8);
        }
        for (int idx = tid; idx < BN * 4; idx += 256) {
            int r = idx >> 2, s = (idx & 3) * 8;
            load16(Bh + (size_t)r * ldb + c * 32 + s, sBh + idx * 8);
            load16(Bl + (size_t)r * ldb + c * 32 + s, sBl + idx * 8);
        }
        asm volatile("s_waitcnt vmcnt(0)" ::: "memory");
        __syncthreads();

        halfx8 ahf[FM], alf[FM], bhf[FN], blf[FN];
        #pragma unroll
        for (int i = 0; i < FM; ++i) {
            ahf[i] = *(const halfx8*)(sAh + (arow + i * 16 + rr) * 32 + koff);
            alf[i] = *(const halfx8*)(sAl + (arow + i * 16 + rr) * 32 + koff);
        }
        #pragma unroll
        for (int j = 0; j < FN; ++j) {
            bhf[j] = *(const halfx8*)(sBh + (brow + j * 16 + rr) * 32 + koff);
            blf[j] = *(const halfx8*)(sBl + (brow + j * 16 + rr) * 32 + koff);
        }
        #pragma unroll
        for (int i = 0; i < FM; ++i)
            #pragma unroll
            for (int j = 0; j < FN; ++j) {
                acc[i][j] = __builtin_amdgcn_mfma_f32_16x16x32_f16(ahf[i], bhf[j], acc[i][j], 0, 0, 0);
                acc[i][j] = __builtin_amdgcn_mfma_f32_16x16x32_f16(ahf[i], blf[j], acc[i][j], 0, 0, 0);
                acc[i][j] = __builtin_amdgcn_mfma_f32_16x16x32_f16(alf[i], bhf[j], acc[i][j], 0, 0, 0);
            }
        __syncthreads();
    }
}

// ---------------------------------------------------------------------------
__global__ __launch_bounds__(256) void k_zero(float* __restrict__ a, int n) {
    int i = blockIdx.x * 256 + threadIdx.x;
    if (i < n) a[i] = 0.f;
}

// split all static operands to hi/lo fp16 (dtw padded K 48->64), float4/thread
__global__ __launch_bounds__(256) void k_splitall(
        const float* __restrict__ hs,  const float* __restrict__ wip,
        const float* __restrict__ wop, const float* __restrict__ xw,
        const float* __restrict__ dtw,
        _Float16* __restrict__ hsh,  _Float16* __restrict__ hsl,
        _Float16* __restrict__ wiph, _Float16* __restrict__ wipl,
        _Float16* __restrict__ woph, _Float16* __restrict__ wopl,
        _Float16* __restrict__ xwh,  _Float16* __restrict__ xwl,
        _Float16* __restrict__ dtwh, _Float16* __restrict__ dtwl) {
    int i4 = (blockIdx.x * 256 + threadIdx.x) * 4;
    floatx4 v;
    _Float16 *dh, *dl; int off;
    if (i4 < 786432)        { off = i4;           v = *(const floatx4*)(hs + off);  dh = hsh;  dl = hsl;  }
    else if (i4 < 3145728)  { off = i4 - 786432;  v = *(const floatx4*)(wip + off); dh = wiph; dl = wipl; }
    else if (i4 < 4325376)  { off = i4 - 3145728; v = *(const floatx4*)(wop + off); dh = woph; dl = wopl; }
    else if (i4 < 4816896)  { off = i4 - 4325376; v = *(const floatx4*)(xw + off);  dh = xwh;  dl = xwl;  }
    else {
        int t0 = i4 - 4816896;          // [dir*1536 + d][64] padded
        int col = t0 & 63, dr = t0 >> 6;
        floatx4 z = {0.f, 0.f, 0.f, 0.f};
        v = (col < 48) ? *(const floatx4*)(dtw + (size_t)dr * 48 + col) : z;
        dh = dtwh; dl = dtwl; off = t0;
    }
    halfx4 hh, hl;
    #pragma unroll
    for (int e = 0; e < 4; ++e) {
        _Float16 h = (_Float16)v[e];
        hh[e] = h; hl[e] = (_Float16)(v[e] - (float)h);
    }
    *(halfx4*)(dh + off) = hh;
    *(halfx4*)(dl + off) = hl;
}

// ---------------------------------------------------------------------------
// in_proj: (1024x768)*(3072x768)^T, 128x128 tile, K-split 2 -> two partial
// fp32 planes (consumers sum them; no atomics).
__global__ __launch_bounds__(256) void k_inproj_t(const _Float16* __restrict__ Ah,
                                                  const _Float16* __restrict__ Al,
                                                  const _Float16* __restrict__ Bh,
                                                  const _Float16* __restrict__ Bl,
                                                  float* __restrict__ C) {
    __shared__ _Float16 smem[128 * 64 + 128 * 64];
    int row0 = blockIdx.x * 128, col0 = blockIdx.y * 128, k0 = blockIdx.z * 384;
    float* Cp = C + (size_t)blockIdx.z * MROWS * F2D;
    floatx4 acc[4][4] = {};
    gemm_core<128, 128, 2, 4, 4>(Ah + (size_t)row0 * EI + k0, Al + (size_t)row0 * EI + k0, EI,
                                 Bh + (size_t)col0 * EI + k0, Bl + (size_t)col0 * EI + k0, EI,
                                 12, smem, acc);
    int lane = threadIdx.x & 63, wave = threadIdx.x >> 6;
    int cc = lane & 15, q = lane >> 4;
    int rbase = row0 + (wave >> 1) * 64, cbase = col0 + (wave & 1) * 64;
    #pragma unroll
    for (int i = 0; i < 4; ++i)
        #pragma unroll
        for (int j = 0; j < 4; ++j)
            #pragma unroll
            for (int r = 0; r < 4; ++r)
                Cp[(size_t)(rbase + i * 16 + q * 4 + r) * F2D + cbase + j * 16 + cc] = acc[i][j][r];
}

// out_proj: (1024x1536)*(768x1536)^T -> out fp32 (1024x768), K-split x4 + atomic
__global__ __launch_bounds__(256) void k_outproj_t(const _Float16* __restrict__ Ah,
                                                   const _Float16* __restrict__ Al,
                                                   const _Float16* __restrict__ Bh,
                                                   const _Float16* __restrict__ Bl,
                                                   float* __restrict__ C) {
    __shared__ _Float16 smem[192 * 64];
    int row0 = blockIdx.x * 64, col0 = blockIdx.y * 128, k0 = blockIdx.z * 384;
    floatx4 acc[2][4] = {};
    gemm_core<64, 128, 2, 2, 4>(Ah + (size_t)row0 * DI + k0, Al + (size_t)row0 * DI + k0, DI,
                                Bh + (size_t)col0 * DI + k0, Bl + (size_t)col0 * DI + k0, DI,
                                12, smem, acc);
    int lane = threadIdx.x & 63, wave = threadIdx.x >> 6;
    int cc = lane & 15, q = lane >> 4;
    int rbase = row0 + (wave >> 1) * 32, cbase = col0 + (wave & 1) * 64;
    #pragma unroll
    for (int i = 0; i < 2; ++i)
        #pragma unroll
        for (int j = 0; j < 4; ++j)
            #pragma unroll
            for (int r = 0; r < 4; ++r)
                atomicAdd(&C[(size_t)(rbase + i * 16 + q * 4 + r) * EI + cbase + j * 16 + cc], acc[i][j][r]);
}

// x_dbl: per dir (1024x1536)*(80x1536)^T -> xdbl_acc fp32, K-split x8 + atomic
__global__ __launch_bounds__(256) void k_xdbl_t(const _Float16* __restrict__ xh,
                                                const _Float16* __restrict__ xl,
                                                const _Float16* __restrict__ xwh,
                                                const _Float16* __restrict__ xwl,
                                                float* __restrict__ C) {
    __shared__ _Float16 smem[208 * 64];
    int row0 = blockIdx.x * 128, dir = blockIdx.y, k0 = blockIdx.z * 192;
    floatx4 acc[2][5] = {};
    const size_t abase = ((size_t)dir * MROWS + row0) * DI + k0;
    const size_t bbase = (size_t)dir * 80 * DI + k0;
    gemm_core<128, 80, 1, 2, 5>(xh + abase, xl + abase, DI,
                                xwh + bbase, xwl + bbase, DI, 6, smem, acc);
    int lane = threadIdx.x & 63, wave = threadIdx.x >> 6;
    int cc = lane & 15, q = lane >> 4;
    int rbase = row0 + wave * 32;
    #pragma unroll
    for (int i = 0; i < 2; ++i)
        #pragma unroll
        for (int j = 0; j < 5; ++j)
            #pragma unroll
            for (int r = 0; r < 4; ++r)
                atomicAdd(&C[((size_t)dir * MROWS + rbase + i * 16 + q * 4 + r) * 80 + j * 16 + cc],
                          acc[i][j][r]);
}

// xdbl epilogue: split cols -> dtq hi/lo (padded to 64), interleaved (B,C)
// pairs into BCm. 96 cols per row (race-free mapping).
__global__ __launch_bounds__(256) void k_xsplit(const float* __restrict__ acc,
                                                _Float16* __restrict__ dtqh,
                                                _Float16* __restrict__ dtql,
                                                float* __restrict__ BCm) {
    int idx = blockIdx.x * 256 + threadIdx.x;   // < 4*1024*96
    int dir = idx / (MROWS * 96);
    int rem = idx - dir * MROWS * 96;
    int row = rem / 96, col = rem - row * 96;
    size_t rbase = (size_t)dir * MROWS + row;
    if (col < 64) {
        float v = (col < 48) ? acc[rbase * 80 + col] : 0.f;
        _Float16 h = (_Float16)v;
        dtqh[rbase * 64 + col] = h;
        dtql[rbase * 64 + col] = (_Float16)(v - (float)h);
    } else if (col < 80) {
        int n = col - 64;
        BCm[rbase * 32 + n * 2] = acc[rbase * 80 + 48 + n];       // B
    } else {
        int n = col - 80;
        BCm[rbase * 32 + n * 2 + 1] = acc[rbase * 80 + 64 + n];   // C
    }
}

// delta: per dir (1024x64pad)*(1536x64pad)^T, epilogue softplus(.+dtb) -> fp32
__global__ __launch_bounds__(256) void k_delta_t(const _Float16* __restrict__ dtqh,
                                                 const _Float16* __restrict__ dtql,
                                                 const _Float16* __restrict__ dtwh,
                                                 const _Float16* __restrict__ dtwl,
                                                 const float* __restrict__ dtb,
                                                 float* __restrict__ delta) {
    __shared__ _Float16 smem[192 * 64];
    int row0 = blockIdx.x * 64, col0 = blockIdx.y * 128, dir = blockIdx.z;
    floatx4 acc[2][4] = {};
    const size_t abase = ((size_t)dir * MROWS + row0) * 64;
    const size_t bbase = ((size_t)dir * DI + col0) * 64;
    gemm_core<64, 128, 2, 2, 4>(dtqh + abase, dtql + abase, 64,
                                dtwh + bbase, dtwl + bbase, 64, 2, smem, acc);
    int lane = threadIdx.x & 63, wave = threadIdx.x >> 6;
    int cc = lane & 15, q = lane >> 4;
    int rbase = row0 + (wave >> 1) * 32, cbase = col0 + (wave & 1) * 64;
    #pragma unroll
    for (int i = 0; i < 2; ++i)
        #pragma unroll
        for (int j = 0; j < 4; ++j) {
            int col = cbase + j * 16 + cc;
            float bias = dtb[(size_t)dir * DI + col];
            #pragma unroll
            for (int r = 0; r < 4; ++r) {
                float v = acc[i][j][r] + bias;
                float sp = (v > 20.f) ? v : log1pf(__expf(v));
                delta[((size_t)dir * MROWS + rbase + i * 16 + q * 4 + r) * DI + col] = sp;
            }
        }
}

// ---------------------------------------------------------------------------
// Depthwise causal conv (K=4) + bias + silu on permuted xz (sum of 2 planes),
// output split to hi/lo fp16 [dir][b*256+l_scan][D].
__global__ __launch_bounds__(256) void k_conv(const float* __restrict__ xz,
                                              const float* __restrict__ cw,
                                              const float* __restrict__ cb,
                                              _Float16* __restrict__ xh,
                                              _Float16* __restrict__ xl) {
    const size_t S = (size_t)MROWS * F2D;
    int dir = blockIdx.z;
    int bl = blockIdx.x;
    int b = bl >> 8, l = bl & 255;
    int d = blockIdx.y * 256 + threadIdx.x;
    const float* w = cw + ((size_t)dir * DI + d) * KI;
    float s = cb[(size_t)dir * DI + d];
    #pragma unroll
    for (int k = 0; k < KI; ++k) {
        int m = l - 3 + k;
        if (m >= 0) {
            int src = perm_idx(dir, m);
            size_t o = ((size_t)b * 256 + src) * F2D + d;
            s += w[k] * (xz[o] + xz[S + o]);
        }
    }
    float x = s / (1.f + __expf(-s));
    _Float16 h = (_Float16)x;
    size_t o = ((size_t)dir * MROWS + bl) * DI + d;
    xh[o] = h;
    xl[o] = (_Float16)(x - (float)h);
}

// ---------------------------------------------------------------------------
// Selective scan v3: block = 32 d x 8 n-pairs, 128B-aligned staging rows,
// DPP 8-lane reduction, software-pipelined double-buffered LDS.
// ---------------------------------------------------------------------------
__global__ __launch_bounds__(256) void k_scan(const float* __restrict__ delta,
                                              const _Float16* __restrict__ xhg,
                                              const _Float16* __restrict__ xlg,
                                              const float* __restrict__ xz,
                                              const float* __restrict__ BCm,
                                              const float* __restrict__ A_log,
                                              const float* __restrict__ Dp,
                                              float* __restrict__ ydir) {
    const size_t S = (size_t)MROWS * F2D;
    const int dchunk = blockIdx.x, b = blockIdx.y, dir = blockIdx.z;
    const int tid = threadIdx.x;
    const int dslot = tid >> 3;        // 0..31
    const int np = tid & 7;            // n-pair index
    const int d0 = dchunk * 32, d = d0 + dslot;

    __shared__ float sdx[2][32][64];   // [buf][jj][dslot*2 + {0:delta,1:x}]
    __shared__ float sbc[2][32][32];   // [buf][jj][n*2 + {0:B,1:C}]
    __shared__ float sY[32][32];

    const float Av0 = -__expf(A_log[((size_t)dir * DI + d) * NI + 2 * np]);
    const float Av1 = -__expf(A_log[((size_t)dir * DI + d) * NI + 2 * np + 1]);
    const float Dpar = Dp[(size_t)dir * DI + d];
    float h0 = 0.f, h1 = 0.f;

    const size_t dirrow = (size_t)dir * MROWS;
    const int srow = tid >> 3, sc4 = (tid & 7) * 4;   // staging roles

    floatx4 rdel, rbc, rz;
    halfx4 rxh, rxl;
    auto load_chunk = [&](int j0) {
        int row = b * 256 + j0 + srow;
        size_t o = (dirrow + row) * DI + d0 + sc4;
        rdel = *(const floatx4*)(delta + o);
        rxh  = *(const halfx4*)(xhg + o);
        rxl  = *(const halfx4*)(xlg + o);
        rbc  = *(const floatx4*)(BCm + (dirrow + row) * 32 + sc4);
        int lsrc = perm_idx(dir, j0 + srow);
        size_t zo = ((size_t)b * 256 + lsrc) * F2D + DI + d0 + sc4;
        floatx4 z0 = *(const floatx4*)(xz + zo);
        floatx4 z1 = *(const floatx4*)(xz + S + zo);
        rz = z0 + z1;
    };

    load_chunk(0);

    for (int c = 0; c < 8; ++c) {
        const int buf = c & 1;
        // stage chunk c
        #pragma unroll
        for (int e = 0; e < 4; ++e) {
            sdx[buf][srow][(sc4 + e) * 2]     = rdel[e];
            sdx[buf][srow][(sc4 + e) * 2 + 1] = (float)rxh[e] + (float)rxl[e];
        }
        *(floatx4*)&sbc[buf][srow][sc4] = rbc;
        floatx4 zs = rz;
        __syncthreads();                       // chunk c visible; sY free
        if (c < 7) load_chunk((c + 1) * 32);   // prefetch, no wait

        // ---- 32 recurrence steps ----
        #pragma unroll
        for (int jj = 0; jj < 32; ++jj) {
            floatx2 dx = *(const floatx2*)&sdx[buf][jj][dslot * 2];
            floatx4 bc = *(const floatx4*)&sbc[buf][jj][np * 4];  // B0,C0,B1,C1
            float dv = dx[0], xv = dx[1];
            float a0 = __expf(dv * Av0);
            float a1 = __expf(dv * Av1);
            float du = dv * xv;
            h0 = fmaf(a0, h0, du * bc[0]);
            h1 = fmaf(a1, h1, du * bc[2]);
            float p = fmaf(h1, bc[3], h0 * bc[1]);
            p = grp8_sum(p);
            if (np == 0) sY[jj][dslot] = fmaf(Dpar, xv, p);
        }
        __syncthreads();                       // sY complete

        // ---- gated write to out-domain (4 floats/thread, 128B rows) ----
        {
            int lout = perm_idx(dir, c * 32 + srow);
            floatx4 o;
            #pragma unroll
            for (int e = 0; e < 4; ++e) {
                float zv = zs[e];
                float g = zv / (1.f + __expf(-zv));
                o[e] = sY[srow][sc4 + e] * g;
            }
            *(floatx4*)&ydir[(dirrow + (size_t)b * 256 + lout) * DI + d0 + sc4] = o;
        }
    }
}

// sum of 4 direction outputs -> hi/lo fp16 for out_proj A-operand (float4)
__global__ __launch_bounds__(256) void k_sum(const float* __restrict__ ydir,
                                             _Float16* __restrict__ yh,
                                             _Float16* __restrict__ yl) {
    int i4 = (blockIdx.x * 256 + threadIdx.x) * 4;
    const size_t S = (size_t)MROWS * DI;
    floatx4 s = *(const floatx4*)(ydir + i4) + *(const floatx4*)(ydir + S + i4) +
                *(const floatx4*)(ydir + 2 * S + i4) + *(const floatx4*)(ydir + 3 * S + i4);
    halfx4 hh, hl;
    #pragma unroll
    for (int e = 0; e < 4; ++e) {
        _Float16 h = (_Float16)s[e];
        hh[e] = h; hl[e] = (_Float16)(s[e] - (float)h);
    }
    *(halfx4*)(yh + i4) = hh;
    *(halfx4*)(yl + i4) = hl;
}

// ---------------------------------------------------------------------------
extern "C" void kernel_launch(void* const* d_in, const int* in_sizes, int n_in,
                              void* d_out, int out_size, void* d_ws, size_t ws_size,
                              hipStream_t stream) {
    const float* hs   = (const float*)d_in[0];
    const float* wip  = (const float*)d_in[1];
    const float* wop  = (const float*)d_in[2];
    const float* cw   = (const float*)d_in[3];
    const float* cb   = (const float*)d_in[4];
    const float* xw   = (const float*)d_in[5];
    const float* dtw  = (const float*)d_in[6];
    const float* dtb  = (const float*)d_in[7];
    const float* alog = (const float*)d_in[8];
    const float* dpar = (const float*)d_in[9];
    float* out = (float*)d_out;

    char* p = (char*)d_ws;
    auto alloc_f32 = [&](size_t n) { float* r = (float*)p; p += n * 4; return r; };
    auto alloc_f16 = [&](size_t n) { _Float16* r = (_Float16*)p; p += n * 2; return r; };

    _Float16* hsh  = alloc_f16(786432);
    _Float16* hsl  = alloc_f16(786432);
    _Float16* wiph = alloc_f16(2359296);
    _Float16* wipl = alloc_f16(2359296);
    _Float16* woph = alloc_f16(1179648);
    _Float16* wopl = alloc_f16(1179648);
    _Float16* xwh  = alloc_f16(491520);
    _Float16* xwl  = alloc_f16(491520);
    _Float16* dtwh = alloc_f16((size_t)NDIRS * DI * 64);
    _Float16* dtwl = alloc_f16((size_t)NDIRS * DI * 64);
    float*    xz   = alloc_f32((size_t)2 * MROWS * F2D);   // two K-split planes
    _Float16* xh   = alloc_f16((size_t)NDIRS * MROWS * DI);
    _Float16* xl   = alloc_f16((size_t)NDIRS * MROWS * DI);
    float*    xdba = alloc_f32((size_t)NDIRS * MROWS * 80);
    _Float16* dtqh = alloc_f16((size_t)NDIRS * MROWS * 64);
    _Float16* dtql = alloc_f16((size_t)NDIRS * MROWS * 64);
    float*    BCm  = alloc_f32((size_t)NDIRS * MROWS * 32);
    float*    delta= alloc_f32((size_t)NDIRS * MROWS * DI);
    float*    ydir = alloc_f32((size_t)NDIRS * MROWS * DI);
    _Float16* yh   = alloc_f16((size_t)MROWS * DI);
    _Float16* yl   = alloc_f16((size_t)MROWS * DI);

    k_zero    <<<dim3(1280), 256, 0, stream>>>(xdba, NDIRS * MROWS * 80);
    k_zero    <<<dim3(3072), 256, 0, stream>>>(out, MROWS * EI);
    k_splitall<<<dim3(5088), 256, 0, stream>>>(hs, wip, wop, xw, dtw,
                                               hsh, hsl, wiph, wipl, woph, wopl,
                                               xwh, xwl, dtwh, dtwl);
    k_inproj_t<<<dim3(8, 24, 2), 256, 0, stream>>>(hsh, hsl, wiph, wipl, xz);
    k_conv    <<<dim3(MROWS, DI / 256, NDIRS), 256, 0, stream>>>(xz, cw, cb, xh, xl);
    k_xdbl_t  <<<dim3(8, NDIRS, 8), 256, 0, stream>>>(xh, xl, xwh, xwl, xdba);
    k_xsplit  <<<dim3(1536), 256, 0, stream>>>(xdba, dtqh, dtql, BCm);
    k_delta_t <<<dim3(16, 12, NDIRS), 256, 0, stream>>>(dtqh, dtql, dtwh, dtwl, dtb, delta);
    k_scan    <<<dim3(DI / 32, BI, NDIRS), 256, 0, stream>>>(delta, xh, xl, xz, BCm,
                                                             alog, dpar, ydir);
    k_sum     <<<dim3(1536), 256, 0, stream>>>(ydir, yh, yl);
    k_outproj_t<<<dim3(16, 6, 4), 256, 0, stream>>>(yh, yl, woph, wopl, out);
}

// Round 7
// 235.037 us; speedup vs baseline: 2.1421x; 1.1495x over previous
//
#include <hip/hip_runtime.h>
#include <hip/hip_bf16.h>

#define BI   4
#define LI   256
#define EI   768
#define DI   1536
#define NI   16
#define RI   48
#define KI   4
#define NDIRS 4
#define F2D  3072              // 2*D
#define MROWS 1024             // B*L
#define LOG2E 1.4426950408889634f

typedef float    floatx2 __attribute__((ext_vector_type(2)));
typedef float    floatx4 __attribute__((ext_vector_type(4)));
typedef _Float16 halfx2  __attribute__((ext_vector_type(2)));
typedef _Float16 halfx4  __attribute__((ext_vector_type(4)));
typedef _Float16 halfx8  __attribute__((ext_vector_type(8)));

typedef __attribute__((address_space(3))) unsigned lds_u32;
typedef __attribute__((address_space(1))) const unsigned glb_u32;

__device__ __forceinline__ void load16(const _Float16* g, _Float16* l) {
    __builtin_amdgcn_global_load_lds((glb_u32*)g, (lds_u32*)l, 16, 0, 0);
}

__device__ __forceinline__ int perm_idx(int dir, int j) {
    switch (dir) {
        case 0:  return j;
        case 1:  return 255 - j;
        case 2:  return ((j & 15) << 4) | (j >> 4);
        default: return 255 - (((j & 15) << 4) | (j >> 4));
    }
}

// DPP-based add of a permuted copy (VALU pipe, no LDS traffic).
template<int CTRL>
__device__ __forceinline__ float dpp_add(float p) {
    int t = __builtin_amdgcn_update_dpp(0, __builtin_bit_cast(int, p),
                                        CTRL, 0xf, 0xf, true);
    return p + __builtin_bit_cast(float, t);
}
// sum over 8 consecutive lanes (tid&7 group)
__device__ __forceinline__ float grp8_sum(float p) {
    p = dpp_add<0xB1>(p);    // quad_perm [1,0,3,2]  : xor 1
    p = dpp_add<0x4E>(p);    // quad_perm [2,3,0,1]  : xor 2
    p = dpp_add<0x141>(p);   // row_half_mirror      : combine quads
    return p;
}

// ---------------------------------------------------------------------------
// Tiled hi/lo-fp16 GEMM core. LDS tiles [rows][32] fp16, unpadded
// (global_load_lds lane-order). acc += ah*bh + ah*bl + al*bh.
// ---------------------------------------------------------------------------
template<int BM, int BN, int WGN, int FM, int FN>
__device__ __forceinline__ void gemm_core(const _Float16* __restrict__ Ah,
                                          const _Float16* __restrict__ Al, int lda,
                                          const _Float16* __restrict__ Bh,
                                          const _Float16* __restrict__ Bl, int ldb,
                                          int nChunks, _Float16* smem,
                                          floatx4 (&acc)[FM][FN]) {
    const int tid = threadIdx.x, lane = tid & 63, wave = tid >> 6;
    const int wave_m = wave / WGN, wave_n = wave % WGN;
    _Float16* sAh = smem;
    _Float16* sAl = smem + BM * 32;
    _Float16* sBh = smem + BM * 64;
    _Float16* sBl = smem + BM * 64 + BN * 32;
    const int rr = lane & 15, koff = (lane >> 4) * 8;
    const int arow = wave_m * FM * 16, brow = wave_n * FN * 16;

    for (int c = 0; c < nChunks; ++c) {
        for (int idx = tid; idx < BM * 4; idx += 256) {
            int r = idx >> 2, s = (idx & 3) * 8;
            load16(Ah + (size_t)r * lda + c * 32 + s, sAh + idx * 8);
            load16(Al + (size_t)r * lda + c * 32 + s, sAl + idx * 8);
        }
        for (int idx = tid; idx < BN * 4; idx += 256) {
            int r = idx >> 2, s = (idx & 3) * 8;
            load16(Bh + (size_t)r * ldb + c * 32 + s, sBh + idx * 8);
            load16(Bl + (size_t)r * ldb + c * 32 + s, sBl + idx * 8);
        }
        asm volatile("s_waitcnt vmcnt(0)" ::: "memory");
        __syncthreads();

        halfx8 ahf[FM], alf[FM], bhf[FN], blf[FN];
        #pragma unroll
        for (int i = 0; i < FM; ++i) {
            ahf[i] = *(const halfx8*)(sAh + (arow + i * 16 + rr) * 32 + koff);
            alf[i] = *(const halfx8*)(sAl + (arow + i * 16 + rr) * 32 + koff);
        }
        #pragma unroll
        for (int j = 0; j < FN; ++j) {
            bhf[j] = *(const halfx8*)(sBh + (brow + j * 16 + rr) * 32 + koff);
            blf[j] = *(const halfx8*)(sBl + (brow + j * 16 + rr) * 32 + koff);
        }
        #pragma unroll
        for (int i = 0; i < FM; ++i)
            #pragma unroll
            for (int j = 0; j < FN; ++j) {
                acc[i][j] = __builtin_amdgcn_mfma_f32_16x16x32_f16(ahf[i], bhf[j], acc[i][j], 0, 0, 0);
                acc[i][j] = __builtin_amdgcn_mfma_f32_16x16x32_f16(ahf[i], blf[j], acc[i][j], 0, 0, 0);
                acc[i][j] = __builtin_amdgcn_mfma_f32_16x16x32_f16(alf[i], bhf[j], acc[i][j], 0, 0, 0);
            }
        __syncthreads();
    }
}

// ---------------------------------------------------------------------------
// split all static operands to hi/lo fp16 (dtw padded K 48->64), float4/thread
__global__ __launch_bounds__(256) void k_splitall(
        const float* __restrict__ hs,  const float* __restrict__ wip,
        const float* __restrict__ wop, const float* __restrict__ xw,
        const float* __restrict__ dtw,
        _Float16* __restrict__ hsh,  _Float16* __restrict__ hsl,
        _Float16* __restrict__ wiph, _Float16* __restrict__ wipl,
        _Float16* __restrict__ woph, _Float16* __restrict__ wopl,
        _Float16* __restrict__ xwh,  _Float16* __restrict__ xwl,
        _Float16* __restrict__ dtwh, _Float16* __restrict__ dtwl) {
    int i4 = (blockIdx.x * 256 + threadIdx.x) * 4;
    floatx4 v;
    _Float16 *dh, *dl; int off;
    if (i4 < 786432)        { off = i4;           v = *(const floatx4*)(hs + off);  dh = hsh;  dl = hsl;  }
    else if (i4 < 3145728)  { off = i4 - 786432;  v = *(const floatx4*)(wip + off); dh = wiph; dl = wipl; }
    else if (i4 < 4325376)  { off = i4 - 3145728; v = *(const floatx4*)(wop + off); dh = woph; dl = wopl; }
    else if (i4 < 4816896)  { off = i4 - 4325376; v = *(const floatx4*)(xw + off);  dh = xwh;  dl = xwl;  }
    else {
        int t0 = i4 - 4816896;          // [dir*1536 + d][64] padded
        int col = t0 & 63, dr = t0 >> 6;
        floatx4 z = {0.f, 0.f, 0.f, 0.f};
        v = (col < 48) ? *(const floatx4*)(dtw + (size_t)dr * 48 + col) : z;
        dh = dtwh; dl = dtwl; off = t0;
    }
    halfx4 hh, hl;
    #pragma unroll
    for (int e = 0; e < 4; ++e) {
        _Float16 h = (_Float16)v[e];
        hh[e] = h; hl[e] = (_Float16)(v[e] - (float)h);
    }
    *(halfx4*)(dh + off) = hh;
    *(halfx4*)(dl + off) = hl;
}

// ---------------------------------------------------------------------------
// in_proj: (1024x768)*(3072x768)^T, 128x128 tile, K-split 2 -> two partial
// fp32 planes (consumers sum them; no atomics).
__global__ __launch_bounds__(256) void k_inproj_t(const _Float16* __restrict__ Ah,
                                                  const _Float16* __restrict__ Al,
                                                  const _Float16* __restrict__ Bh,
                                                  const _Float16* __restrict__ Bl,
                                                  float* __restrict__ C) {
    __shared__ _Float16 smem[128 * 64 + 128 * 64];
    int row0 = blockIdx.x * 128, col0 = blockIdx.y * 128, k0 = blockIdx.z * 384;
    float* Cp = C + (size_t)blockIdx.z * MROWS * F2D;
    floatx4 acc[4][4] = {};
    gemm_core<128, 128, 2, 4, 4>(Ah + (size_t)row0 * EI + k0, Al + (size_t)row0 * EI + k0, EI,
                                 Bh + (size_t)col0 * EI + k0, Bl + (size_t)col0 * EI + k0, EI,
                                 12, smem, acc);
    int lane = threadIdx.x & 63, wave = threadIdx.x >> 6;
    int cc = lane & 15, q = lane >> 4;
    int rbase = row0 + (wave >> 1) * 64, cbase = col0 + (wave & 1) * 64;
    #pragma unroll
    for (int i = 0; i < 4; ++i)
        #pragma unroll
        for (int j = 0; j < 4; ++j)
            #pragma unroll
            for (int r = 0; r < 4; ++r)
                Cp[(size_t)(rbase + i * 16 + q * 4 + r) * F2D + cbase + j * 16 + cc] = acc[i][j][r];
}

// out_proj: (1024x1536)*(768x1536)^T, K-split x4 -> 4 partial planes (no atomics)
__global__ __launch_bounds__(256) void k_outproj_t(const _Float16* __restrict__ Ah,
                                                   const _Float16* __restrict__ Al,
                                                   const _Float16* __restrict__ Bh,
                                                   const _Float16* __restrict__ Bl,
                                                   float* __restrict__ C) {
    __shared__ _Float16 smem[192 * 64];
    int row0 = blockIdx.x * 64, col0 = blockIdx.y * 128, k0 = blockIdx.z * 384;
    float* Cp = C + (size_t)blockIdx.z * MROWS * EI;
    floatx4 acc[2][4] = {};
    gemm_core<64, 128, 2, 2, 4>(Ah + (size_t)row0 * DI + k0, Al + (size_t)row0 * DI + k0, DI,
                                Bh + (size_t)col0 * DI + k0, Bl + (size_t)col0 * DI + k0, DI,
                                12, smem, acc);
    int lane = threadIdx.x & 63, wave = threadIdx.x >> 6;
    int cc = lane & 15, q = lane >> 4;
    int rbase = row0 + (wave >> 1) * 32, cbase = col0 + (wave & 1) * 64;
    #pragma unroll
    for (int i = 0; i < 2; ++i)
        #pragma unroll
        for (int j = 0; j < 4; ++j)
            #pragma unroll
            for (int r = 0; r < 4; ++r)
                Cp[(size_t)(rbase + i * 16 + q * 4 + r) * EI + cbase + j * 16 + cc] = acc[i][j][r];
}

// final out = sum of 4 out_proj partial planes
__global__ __launch_bounds__(256) void k_osum(const float* __restrict__ oacc,
                                              float* __restrict__ out) {
    int i4 = (blockIdx.x * 256 + threadIdx.x) * 4;
    const size_t S = (size_t)MROWS * EI;
    floatx4 s = *(const floatx4*)(oacc + i4) + *(const floatx4*)(oacc + S + i4) +
                *(const floatx4*)(oacc + 2 * S + i4) + *(const floatx4*)(oacc + 3 * S + i4);
    *(floatx4*)(out + i4) = s;
}

// x_dbl: per dir (1024x1536)*(80x1536)^T, K-split x8 -> 8 partial planes
__global__ __launch_bounds__(256) void k_xdbl_t(const _Float16* __restrict__ xh,
                                                const _Float16* __restrict__ xl,
                                                const _Float16* __restrict__ xwh,
                                                const _Float16* __restrict__ xwl,
                                                float* __restrict__ C) {
    __shared__ _Float16 smem[208 * 64];
    int row0 = blockIdx.x * 128, dir = blockIdx.y, k0 = blockIdx.z * 192;
    float* Cp = C + (size_t)blockIdx.z * NDIRS * MROWS * 80;
    floatx4 acc[2][5] = {};
    const size_t abase = ((size_t)dir * MROWS + row0) * DI + k0;
    const size_t bbase = (size_t)dir * 80 * DI + k0;
    gemm_core<128, 80, 1, 2, 5>(xh + abase, xl + abase, DI,
                                xwh + bbase, xwl + bbase, DI, 6, smem, acc);
    int lane = threadIdx.x & 63, wave = threadIdx.x >> 6;
    int cc = lane & 15, q = lane >> 4;
    int rbase = row0 + wave * 32;
    #pragma unroll
    for (int i = 0; i < 2; ++i)
        #pragma unroll
        for (int j = 0; j < 5; ++j)
            #pragma unroll
            for (int r = 0; r < 4; ++r)
                Cp[((size_t)dir * MROWS + rbase + i * 16 + q * 4 + r) * 80 + j * 16 + cc] = acc[i][j][r];
}

// xdbl epilogue: sum 8 partial planes; split cols -> dtq hi/lo (padded to 64),
// interleaved (B,C) pairs into BCm. 96 cols per row (race-free mapping).
__global__ __launch_bounds__(256) void k_xsplit(const float* __restrict__ acc,
                                                _Float16* __restrict__ dtqh,
                                                _Float16* __restrict__ dtql,
                                                float* __restrict__ BCm) {
    const size_t PS = (size_t)NDIRS * MROWS * 80;
    int idx = blockIdx.x * 256 + threadIdx.x;   // < 4*1024*96
    int dir = idx / (MROWS * 96);
    int rem = idx - dir * MROWS * 96;
    int row = rem / 96, col = rem - row * 96;
    size_t rbase = (size_t)dir * MROWS + row;
    auto sum8 = [&](int c) {
        size_t o = rbase * 80 + c;
        float s = 0.f;
        #pragma unroll
        for (int kp = 0; kp < 8; ++kp) s += acc[kp * PS + o];
        return s;
    };
    if (col < 64) {
        float v = (col < 48) ? sum8(col) : 0.f;
        _Float16 h = (_Float16)v;
        dtqh[rbase * 64 + col] = h;
        dtql[rbase * 64 + col] = (_Float16)(v - (float)h);
    } else if (col < 80) {
        int n = col - 64;
        BCm[rbase * 32 + n * 2] = sum8(48 + n);       // B
    } else {
        int n = col - 80;
        BCm[rbase * 32 + n * 2 + 1] = sum8(64 + n);   // C
    }
}

// delta: per dir (1024x64pad)*(1536x64pad)^T, epilogue softplus(.+dtb) -> fp32
__global__ __launch_bounds__(256) void k_delta_t(const _Float16* __restrict__ dtqh,
                                                 const _Float16* __restrict__ dtql,
                                                 const _Float16* __restrict__ dtwh,
                                                 const _Float16* __restrict__ dtwl,
                                                 const float* __restrict__ dtb,
                                                 float* __restrict__ delta) {
    __shared__ _Float16 smem[192 * 64];
    int row0 = blockIdx.x * 64, col0 = blockIdx.y * 128, dir = blockIdx.z;
    floatx4 acc[2][4] = {};
    const size_t abase = ((size_t)dir * MROWS + row0) * 64;
    const size_t bbase = ((size_t)dir * DI + col0) * 64;
    gemm_core<64, 128, 2, 2, 4>(dtqh + abase, dtql + abase, 64,
                                dtwh + bbase, dtwl + bbase, 64, 2, smem, acc);
    int lane = threadIdx.x & 63, wave = threadIdx.x >> 6;
    int cc = lane & 15, q = lane >> 4;
    int rbase = row0 + (wave >> 1) * 32, cbase = col0 + (wave & 1) * 64;
    #pragma unroll
    for (int i = 0; i < 2; ++i)
        #pragma unroll
        for (int j = 0; j < 4; ++j) {
            int col = cbase + j * 16 + cc;
            float bias = dtb[(size_t)dir * DI + col];
            #pragma unroll
            for (int r = 0; r < 4; ++r) {
                float v = acc[i][j][r] + bias;
                float sp = (v > 20.f) ? v : log1pf(__expf(v));
                delta[((size_t)dir * MROWS + rbase + i * 16 + q * 4 + r) * DI + col] = sp;
            }
        }
}

// ---------------------------------------------------------------------------
// Depthwise causal conv (K=4) + bias + silu, register-window version:
// thread owns (dir,b,d, 16-l tile); 19 staged reads -> 16 outputs.
__global__ __launch_bounds__(256) void k_conv(const float* __restrict__ xz,
                                              const float* __restrict__ cw,
                                              const float* __restrict__ cb,
                                              _Float16* __restrict__ xh,
                                              _Float16* __restrict__ xl) {
    const size_t S = (size_t)MROWS * F2D;
    int dir = blockIdx.z, b = blockIdx.y;
    int lchunk = blockIdx.x / 6, dsub = blockIdx.x % 6;
    int d = dsub * 256 + threadIdx.x;
    int base = lchunk * 16;

    const float* w = cw + ((size_t)dir * DI + d) * KI;
    float w0 = w[0], w1 = w[1], w2 = w[2], w3 = w[3];
    float bias = cb[(size_t)dir * DI + d];

    auto ld = [&](int m) -> float {
        if (m < 0) return 0.f;
        int src = perm_idx(dir, m);
        size_t o = ((size_t)b * 256 + src) * F2D + d;
        return xz[o] + xz[S + o];
    };
    float xm3 = ld(base - 3), xm2 = ld(base - 2), xm1 = ld(base - 1);

    #pragma unroll
    for (int j = 0; j < 16; ++j) {
        float cur = ld(base + j);
        float s = bias + w0 * xm3 + w1 * xm2 + w2 * xm1 + w3 * cur;
        xm3 = xm2; xm2 = xm1; xm1 = cur;
        float x = s / (1.f + __expf(-s));
        _Float16 h = (_Float16)x;
        size_t o = ((size_t)dir * MROWS + b * 256 + base + j) * DI + d;
        xh[o] = h;
        xl[o] = (_Float16)(x - (float)h);
    }
}

// ---------------------------------------------------------------------------
// Selective scan v3: block = 32 d x 8 n-pairs, 128B-aligned staging rows,
// DPP 8-lane reduction, software-pipelined double-buffered LDS, exp2-folded A.
// ---------------------------------------------------------------------------
__global__ __launch_bounds__(256) void k_scan(const float* __restrict__ delta,
                                              const _Float16* __restrict__ xhg,
                                              const _Float16* __restrict__ xlg,
                                              const float* __restrict__ xz,
                                              const float* __restrict__ BCm,
                                              const float* __restrict__ A_log,
                                              const float* __restrict__ Dp,
                                              float* __restrict__ ydir) {
    const size_t S = (size_t)MROWS * F2D;
    const int dchunk = blockIdx.x, b = blockIdx.y, dir = blockIdx.z;
    const int tid = threadIdx.x;
    const int dslot = tid >> 3;        // 0..31
    const int np = tid & 7;            // n-pair index
    const int d0 = dchunk * 32, d = d0 + dslot;

    __shared__ float sdx[2][32][64];   // [buf][jj][dslot*2 + {0:delta,1:x}]
    __shared__ float sbc[2][32][32];   // [buf][jj][n*2 + {0:B,1:C}]
    __shared__ float sY[32][32];

    const float Av0 = -__expf(A_log[((size_t)dir * DI + d) * NI + 2 * np]) * LOG2E;
    const float Av1 = -__expf(A_log[((size_t)dir * DI + d) * NI + 2 * np + 1]) * LOG2E;
    const float Dpar = Dp[(size_t)dir * DI + d];
    float h0 = 0.f, h1 = 0.f;

    const size_t dirrow = (size_t)dir * MROWS;
    const int srow = tid >> 3, sc4 = (tid & 7) * 4;   // staging roles

    floatx4 rdel, rbc, rz;
    halfx4 rxh, rxl;
    auto load_chunk = [&](int j0) {
        int row = b * 256 + j0 + srow;
        size_t o = (dirrow + row) * DI + d0 + sc4;
        rdel = *(const floatx4*)(delta + o);
        rxh  = *(const halfx4*)(xhg + o);
        rxl  = *(const halfx4*)(xlg + o);
        rbc  = *(const floatx4*)(BCm + (dirrow + row) * 32 + sc4);
        int lsrc = perm_idx(dir, j0 + srow);
        size_t zo = ((size_t)b * 256 + lsrc) * F2D + DI + d0 + sc4;
        floatx4 z0 = *(const floatx4*)(xz + zo);
        floatx4 z1 = *(const floatx4*)(xz + S + zo);
        rz = z0 + z1;
    };

    load_chunk(0);

    for (int c = 0; c < 8; ++c) {
        const int buf = c & 1;
        // stage chunk c
        #pragma unroll
        for (int e = 0; e < 4; ++e) {
            sdx[buf][srow][(sc4 + e) * 2]     = rdel[e];
            sdx[buf][srow][(sc4 + e) * 2 + 1] = (float)rxh[e] + (float)rxl[e];
        }
        *(floatx4*)&sbc[buf][srow][sc4] = rbc;
        floatx4 zs = rz;
        __syncthreads();                       // chunk c visible; sY free
        if (c < 7) load_chunk((c + 1) * 32);   // prefetch, no wait

        // ---- 32 recurrence steps ----
        #pragma unroll
        for (int jj = 0; jj < 32; ++jj) {
            floatx2 dx = *(const floatx2*)&sdx[buf][jj][dslot * 2];
            floatx4 bc = *(const floatx4*)&sbc[buf][jj][np * 4];  // B0,C0,B1,C1
            float dv = dx[0], xv = dx[1];
            float a0 = __builtin_amdgcn_exp2f(dv * Av0);
            float a1 = __builtin_amdgcn_exp2f(dv * Av1);
            float du = dv * xv;
            h0 = fmaf(a0, h0, du * bc[0]);
            h1 = fmaf(a1, h1, du * bc[2]);
            float p = fmaf(h1, bc[3], h0 * bc[1]);
            p = grp8_sum(p);
            if (np == 0) sY[jj][dslot] = fmaf(Dpar, xv, p);
        }
        __syncthreads();                       // sY complete

        // ---- gated write to out-domain (4 floats/thread, 128B rows) ----
        {
            int lout = perm_idx(dir, c * 32 + srow);
            floatx4 o;
            #pragma unroll
            for (int e = 0; e < 4; ++e) {
                float zv = zs[e];
                float g = zv / (1.f + __expf(-zv));
                o[e] = sY[srow][sc4 + e] * g;
            }
            *(floatx4*)&ydir[(dirrow + (size_t)b * 256 + lout) * DI + d0 + sc4] = o;
        }
    }
}

// sum of 4 direction outputs -> hi/lo fp16 for out_proj A-operand (float4)
__global__ __launch_bounds__(256) void k_sum(const float* __restrict__ ydir,
                                             _Float16* __restrict__ yh,
                                             _Float16* __restrict__ yl) {
    int i4 = (blockIdx.x * 256 + threadIdx.x) * 4;
    const size_t S = (size_t)MROWS * DI;
    floatx4 s = *(const floatx4*)(ydir + i4) + *(const floatx4*)(ydir + S + i4) +
                *(const floatx4*)(ydir + 2 * S + i4) + *(const floatx4*)(ydir + 3 * S + i4);
    halfx4 hh, hl;
    #pragma unroll
    for (int e = 0; e < 4; ++e) {
        _Float16 h = (_Float16)s[e];
        hh[e] = h; hl[e] = (_Float16)(s[e] - (float)h);
    }
    *(halfx4*)(yh + i4) = hh;
    *(halfx4*)(yl + i4) = hl;
}

// ---------------------------------------------------------------------------
extern "C" void kernel_launch(void* const* d_in, const int* in_sizes, int n_in,
                              void* d_out, int out_size, void* d_ws, size_t ws_size,
                              hipStream_t stream) {
    const float* hs   = (const float*)d_in[0];
    const float* wip  = (const float*)d_in[1];
    const float* wop  = (const float*)d_in[2];
    const float* cw   = (const float*)d_in[3];
    const float* cb   = (const float*)d_in[4];
    const float* xw   = (const float*)d_in[5];
    const float* dtw  = (const float*)d_in[6];
    const float* dtb  = (const float*)d_in[7];
    const float* alog = (const float*)d_in[8];
    const float* dpar = (const float*)d_in[9];
    float* out = (float*)d_out;

    char* p = (char*)d_ws;
    auto alloc_f32 = [&](size_t n) { float* r = (float*)p; p += n * 4; return r; };
    auto alloc_f16 = [&](size_t n) { _Float16* r = (_Float16*)p; p += n * 2; return r; };

    _Float16* hsh  = alloc_f16(786432);
    _Float16* hsl  = alloc_f16(786432);
    _Float16* wiph = alloc_f16(2359296);
    _Float16* wipl = alloc_f16(2359296);
    _Float16* woph = alloc_f16(1179648);
    _Float16* wopl = alloc_f16(1179648);
    _Float16* xwh  = alloc_f16(491520);
    _Float16* xwl  = alloc_f16(491520);
    _Float16* dtwh = alloc_f16((size_t)NDIRS * DI * 64);
    _Float16* dtwl = alloc_f16((size_t)NDIRS * DI * 64);
    float*    xz   = alloc_f32((size_t)2 * MROWS * F2D);   // two K-split planes
    _Float16* xh   = alloc_f16((size_t)NDIRS * MROWS * DI);
    _Float16* xl   = alloc_f16((size_t)NDIRS * MROWS * DI);
    _Float16* dtqh = alloc_f16((size_t)NDIRS * MROWS * 64);
    _Float16* dtql = alloc_f16((size_t)NDIRS * MROWS * 64);
    float*    BCm  = alloc_f32((size_t)NDIRS * MROWS * 32);
    float*    delta= alloc_f32((size_t)NDIRS * MROWS * DI);
    float*    ydir = alloc_f32((size_t)NDIRS * MROWS * DI);
    _Float16* yh   = alloc_f16((size_t)MROWS * DI);
    _Float16* yl   = alloc_f16((size_t)MROWS * DI);

    // aliases onto dead regions (disjoint lifetimes):
    float* xdba = ydir;    // 8 planes * 4*1024*80 = 10.5 MB <= 25.2 MB; dead before scan writes ydir
    float* oacc = delta;   // 4 planes * 1024*768 = 12.6 MB <= 25.2 MB; delta dead after scan

    k_splitall<<<dim3(5088), 256, 0, stream>>>(hs, wip, wop, xw, dtw,
                                               hsh, hsl, wiph, wipl, woph, wopl,
                                               xwh, xwl, dtwh, dtwl);
    k_inproj_t<<<dim3(8, 24, 2), 256, 0, stream>>>(hsh, hsl, wiph, wipl, xz);
    k_conv    <<<dim3(96, BI, NDIRS), 256, 0, stream>>>(xz, cw, cb, xh, xl);
    k_xdbl_t  <<<dim3(8, NDIRS, 8), 256, 0, stream>>>(xh, xl, xwh, xwl, xdba);
    k_xsplit  <<<dim3(1536), 256, 0, stream>>>(xdba, dtqh, dtql, BCm);
    k_delta_t <<<dim3(16, 12, NDIRS), 256, 0, stream>>>(dtqh, dtql, dtwh, dtwl, dtb, delta);
    k_scan    <<<dim3(DI / 32, BI, NDIRS), 256, 0, stream>>>(delta, xh, xl, xz, BCm,
                                                             alog, dpar, ydir);
    k_sum     <<<dim3(1536), 256, 0, stream>>>(ydir, yh, yl);
    k_outproj_t<<<dim3(16, 6, 4), 256, 0, stream>>>(yh, yl, woph, wopl, oacc);
    k_osum    <<<dim3(768), 256, 0, stream>>>(oacc, out);
}